// Round 1
// baseline (696.889 us; speedup 1.0000x reference)
//
#include <hip/hip_runtime.h>
#include <hip/hip_bf16.h>
#include <math.h>

#define D_MODEL 1024
#define D_FF    4096
#define NE      8
#define MT      64   // row tile (M)
#define BK      32   // K step

typedef __bf16 bf16x8 __attribute__((ext_vector_type(8)));
typedef float  f32x4  __attribute__((ext_vector_type(4)));

// ---------------- router: logits, top-2, softmax, x->bf16 ----------------
__global__ __launch_bounds__(256) void router_kernel(
    const float* __restrict__ x, const float* __restrict__ Wg,
    const float* __restrict__ bg, int* __restrict__ topidx,
    float* __restrict__ topw, __bf16* __restrict__ Xb)
{
    int n = blockIdx.x, tid = threadIdx.x;
    const float* xr = x + (size_t)n * D_MODEL;
    int d0 = tid * 4;  // 256 threads * 4 = 1024 = D_MODEL
    float4 xv = *reinterpret_cast<const float4*>(xr + d0);

    // x -> bf16 (packed 4x2B store)
    union { __bf16 h[4]; ushort4 u; } pk;
    pk.h[0] = (__bf16)xv.x; pk.h[1] = (__bf16)xv.y;
    pk.h[2] = (__bf16)xv.z; pk.h[3] = (__bf16)xv.w;
    *reinterpret_cast<ushort4*>(Xb + (size_t)n * D_MODEL + d0) = pk.u;

    float part[NE];
#pragma unroll
    for (int e = 0; e < NE; ++e) part[e] = 0.f;
    float xs[4] = {xv.x, xv.y, xv.z, xv.w};
#pragma unroll
    for (int j = 0; j < 4; ++j) {
        const float4* wr = reinterpret_cast<const float4*>(Wg + (size_t)(d0 + j) * NE);
        float4 w0 = wr[0], w1 = wr[1];
        part[0] += xs[j] * w0.x; part[1] += xs[j] * w0.y;
        part[2] += xs[j] * w0.z; part[3] += xs[j] * w0.w;
        part[4] += xs[j] * w1.x; part[5] += xs[j] * w1.y;
        part[6] += xs[j] * w1.z; part[7] += xs[j] * w1.w;
    }
    // wave (64-lane) reduce
#pragma unroll
    for (int off = 32; off > 0; off >>= 1) {
#pragma unroll
        for (int e = 0; e < NE; ++e) part[e] += __shfl_down(part[e], off);
    }
    __shared__ float sred[4][NE];
    __shared__ float slog[NE];
    int wave = tid >> 6, lane = tid & 63;
    if (lane == 0) {
#pragma unroll
        for (int e = 0; e < NE; ++e) sred[wave][e] = part[e];
    }
    __syncthreads();
    if (tid < NE)
        slog[tid] = bg[tid] + sred[0][tid] + sred[1][tid] + sred[2][tid] + sred[3][tid];
    __syncthreads();
    if (tid == 0) {
        float m0 = -1e30f, m1 = -1e30f; int i0 = 0, i1 = 0;
        for (int e = 0; e < NE; ++e) {
            float l = slog[e];
            if (l > m0)      { m1 = m0; i1 = i0; m0 = l; i0 = e; }
            else if (l > m1) { m1 = l;  i1 = e; }
        }
        float w1 = expf(m1 - m0);   // stable: m0 >= m1
        float s  = 1.f + w1;
        topidx[n * 2 + 0] = i0; topidx[n * 2 + 1] = i1;
        topw[n * 2 + 0] = 1.f / s; topw[n * 2 + 1] = w1 / s;
    }
}

// ---------------- build per-expert padded row lists ----------------
__global__ __launch_bounds__(256) void build_lists_kernel(
    const int* __restrict__ topidx, const float* __restrict__ topw,
    int* __restrict__ pairTok, float* __restrict__ pairW,
    int* __restrict__ rbe, int npairs, int maxrows, int maxblk)
{
    __shared__ int cnt[NE], cur[NE], pof[NE];
    int tid = threadIdx.x;
    if (tid < NE) { cnt[tid] = 0; cur[tid] = 0; }
    for (int i = tid; i < maxrows; i += 256) pairTok[i] = -1;
    for (int i = tid; i < maxblk; i += 256) rbe[i] = -1;
    __syncthreads();
    for (int p = tid; p < npairs; p += 256) atomicAdd(&cnt[topidx[p]], 1);
    __syncthreads();
    if (tid == 0) {
        int off = 0;
        for (int e = 0; e < NE; ++e) { pof[e] = off; off += (cnt[e] + MT - 1) & ~(MT - 1); }
        for (int e = 0; e < NE; ++e) {
            int nb = (cnt[e] + MT - 1) / MT;
            for (int j = 0; j < nb; ++j) rbe[pof[e] / MT + j] = e;
        }
    }
    __syncthreads();
    for (int p = tid; p < npairs; p += 256) {
        int e = topidx[p];
        int pos = atomicAdd(&cur[e], 1);
        int r = pof[e] + pos;
        pairTok[r] = p >> 1;   // token id
        pairW[r]   = topw[p];
    }
}

// ---------------- GEMM1: hidden = gelu(X@W1+b1) * (X@W2+b2) ----------------
__global__ __launch_bounds__(256) void gemm1_kernel(
    const __bf16* __restrict__ Xb, const float* __restrict__ W1,
    const float* __restrict__ W2, const float* __restrict__ b1,
    const float* __restrict__ b2, const int* __restrict__ pairTok,
    const int* __restrict__ rbe, __bf16* __restrict__ hidden)
{
    int b = blockIdx.x;
    int e = rbe[b];
    if (e < 0) return;
    int fblk = blockIdx.y * 128;

    __shared__ __bf16 As[64][40];     // [m][k], pitch 40 (80B, 16B-aligned rows)
    __shared__ __bf16 W1s[128][40];   // [f][k]  (transposed so B-frag is contiguous)
    __shared__ __bf16 W2s[128][40];

    int tid = threadIdx.x;
    int arow = tid >> 2, akoff = (tid & 3) * 8;      // A: 64 rows x 4 thr/row x 8 elems
    int tok = pairTok[b * MT + arow];
    int wk = tid >> 3, wfb = (tid & 7) * 16;         // W: 32 k x 8 thr x 16 f
    const float* w1base = W1 + (size_t)e * D_MODEL * D_FF + (size_t)wk * D_FF + fblk + wfb;
    const float* w2base = W2 + (size_t)e * D_MODEL * D_FF + (size_t)wk * D_FF + fblk + wfb;

    int wave = tid >> 6, lane = tid & 63;
    int wm = (wave >> 1) * 32, wf = (wave & 1) * 64;
    int lm = lane & 15, lk = (lane >> 4) * 8;

    __bf16 z = (__bf16)0.f;
    f32x4 c1[2][4], c2[2][4];
#pragma unroll
    for (int mi = 0; mi < 2; ++mi)
#pragma unroll
        for (int fj = 0; fj < 4; ++fj) {
            c1[mi][fj] = (f32x4){0.f, 0.f, 0.f, 0.f};
            c2[mi][fj] = (f32x4){0.f, 0.f, 0.f, 0.f};
        }

    for (int k0 = 0; k0 < D_MODEL; k0 += BK) {
        __syncthreads();
        // stage A (gathered token rows; padding rows = 0)
        bf16x8 av = {z, z, z, z, z, z, z, z};
        if (tok >= 0)
            av = *reinterpret_cast<const bf16x8*>(Xb + (size_t)tok * D_MODEL + k0 + akoff);
        *reinterpret_cast<bf16x8*>(&As[arow][akoff]) = av;
        // stage W1/W2 transposed, f32 -> bf16
        const float* p1 = w1base + (size_t)k0 * D_FF;
        const float* p2 = w2base + (size_t)k0 * D_FF;
#pragma unroll
        for (int j = 0; j < 4; ++j) {
            float4 v = *reinterpret_cast<const float4*>(p1 + j * 4);
            W1s[wfb + j * 4 + 0][wk] = (__bf16)v.x;
            W1s[wfb + j * 4 + 1][wk] = (__bf16)v.y;
            W1s[wfb + j * 4 + 2][wk] = (__bf16)v.z;
            W1s[wfb + j * 4 + 3][wk] = (__bf16)v.w;
            float4 u = *reinterpret_cast<const float4*>(p2 + j * 4);
            W2s[wfb + j * 4 + 0][wk] = (__bf16)u.x;
            W2s[wfb + j * 4 + 1][wk] = (__bf16)u.y;
            W2s[wfb + j * 4 + 2][wk] = (__bf16)u.z;
            W2s[wfb + j * 4 + 3][wk] = (__bf16)u.w;
        }
        __syncthreads();

        bf16x8 a0 = *reinterpret_cast<bf16x8*>(&As[wm + lm][lk]);
        bf16x8 a1 = *reinterpret_cast<bf16x8*>(&As[wm + 16 + lm][lk]);
#pragma unroll
        for (int fj = 0; fj < 4; ++fj) {
            bf16x8 bw1 = *reinterpret_cast<bf16x8*>(&W1s[wf + fj * 16 + lm][lk]);
            c1[0][fj] = __builtin_amdgcn_mfma_f32_16x16x32_bf16(a0, bw1, c1[0][fj], 0, 0, 0);
            c1[1][fj] = __builtin_amdgcn_mfma_f32_16x16x32_bf16(a1, bw1, c1[1][fj], 0, 0, 0);
            bf16x8 bw2 = *reinterpret_cast<bf16x8*>(&W2s[wf + fj * 16 + lm][lk]);
            c2[0][fj] = __builtin_amdgcn_mfma_f32_16x16x32_bf16(a0, bw2, c2[0][fj], 0, 0, 0);
            c2[1][fj] = __builtin_amdgcn_mfma_f32_16x16x32_bf16(a1, bw2, c2[1][fj], 0, 0, 0);
        }
    }

    // epilogue: exact gelu(h1) * h2 -> bf16 hidden
    int r0 = b * MT;
#pragma unroll
    for (int fj = 0; fj < 4; ++fj) {
        int f = fblk + wf + fj * 16 + lm;
        float b1v = b1[e * D_FF + f];
        float b2v = b2[e * D_FF + f];
#pragma unroll
        for (int mi = 0; mi < 2; ++mi)
#pragma unroll
            for (int r = 0; r < 4; ++r) {
                int m = wm + mi * 16 + (lane >> 4) * 4 + r;
                float h1 = c1[mi][fj][r] + b1v;
                float h2 = c2[mi][fj][r] + b2v;
                float g = 0.5f * h1 * (1.f + erff(h1 * 0.70710678118654752f));
                hidden[(size_t)(r0 + m) * D_FF + f] = (__bf16)(g * h2);
            }
    }
}

// ---------------- GEMM2: out += w * (hidden@W3 + b3) ----------------
__global__ __launch_bounds__(256) void gemm2_kernel(
    const __bf16* __restrict__ hidden, const float* __restrict__ W3,
    const float* __restrict__ b3, const int* __restrict__ pairTok,
    const float* __restrict__ pairW, const int* __restrict__ rbe,
    float* __restrict__ out)
{
    int b = blockIdx.x;
    int e = rbe[b];
    if (e < 0) return;
    int dblk = blockIdx.y * 128;

    __shared__ __bf16 As[64][40];
    __shared__ __bf16 W3s[128][40];

    int tid = threadIdx.x;
    int arow = tid >> 2, akoff = (tid & 3) * 8;
    const __bf16* ap = hidden + (size_t)(b * MT + arow) * D_FF + akoff;
    int wk = tid >> 3, wdb = (tid & 7) * 16;
    const float* w3base = W3 + (size_t)e * D_FF * D_MODEL + (size_t)wk * D_MODEL + dblk + wdb;

    int wave = tid >> 6, lane = tid & 63;
    int wm = (wave >> 1) * 32, wf = (wave & 1) * 64;
    int lm = lane & 15, lk = (lane >> 4) * 8;

    f32x4 c[2][4];
#pragma unroll
    for (int mi = 0; mi < 2; ++mi)
#pragma unroll
        for (int dj = 0; dj < 4; ++dj) c[mi][dj] = (f32x4){0.f, 0.f, 0.f, 0.f};

    for (int k0 = 0; k0 < D_FF; k0 += BK) {
        __syncthreads();
        *reinterpret_cast<bf16x8*>(&As[arow][akoff]) =
            *reinterpret_cast<const bf16x8*>(ap + k0);
        const float* p3 = w3base + (size_t)k0 * D_MODEL;
#pragma unroll
        for (int j = 0; j < 4; ++j) {
            float4 v = *reinterpret_cast<const float4*>(p3 + j * 4);
            W3s[wdb + j * 4 + 0][wk] = (__bf16)v.x;
            W3s[wdb + j * 4 + 1][wk] = (__bf16)v.y;
            W3s[wdb + j * 4 + 2][wk] = (__bf16)v.z;
            W3s[wdb + j * 4 + 3][wk] = (__bf16)v.w;
        }
        __syncthreads();

        bf16x8 a0 = *reinterpret_cast<bf16x8*>(&As[wm + lm][lk]);
        bf16x8 a1 = *reinterpret_cast<bf16x8*>(&As[wm + 16 + lm][lk]);
#pragma unroll
        for (int dj = 0; dj < 4; ++dj) {
            bf16x8 bw = *reinterpret_cast<bf16x8*>(&W3s[wf + dj * 16 + lm][lk]);
            c[0][dj] = __builtin_amdgcn_mfma_f32_16x16x32_bf16(a0, bw, c[0][dj], 0, 0, 0);
            c[1][dj] = __builtin_amdgcn_mfma_f32_16x16x32_bf16(a1, bw, c[1][dj], 0, 0, 0);
        }
    }

    int r0 = b * MT;
#pragma unroll
    for (int dj = 0; dj < 4; ++dj) {
        int d = dblk + wf + dj * 16 + lm;
        float b3v = b3[e * D_MODEL + d];
#pragma unroll
        for (int mi = 0; mi < 2; ++mi)
#pragma unroll
            for (int r = 0; r < 4; ++r) {
                int m = wm + mi * 16 + (lane >> 4) * 4 + r;
                int gr = r0 + m;
                int tok = pairTok[gr];
                if (tok >= 0) {
                    float val = c[mi][dj][r] + b3v;
                    atomicAdd(out + (size_t)tok * D_MODEL + d, pairW[gr] * val);
                }
            }
    }
}

extern "C" void kernel_launch(void* const* d_in, const int* in_sizes, int n_in,
                              void* d_out, int out_size, void* d_ws, size_t ws_size,
                              hipStream_t stream)
{
    const float* x  = (const float*)d_in[0];
    const float* Wg = (const float*)d_in[1];
    const float* bg = (const float*)d_in[2];
    const float* W1 = (const float*)d_in[3];
    const float* b1 = (const float*)d_in[4];
    const float* W2 = (const float*)d_in[5];
    const float* b2 = (const float*)d_in[6];
    const float* W3 = (const float*)d_in[7];
    const float* b3 = (const float*)d_in[8];
    float* out = (float*)d_out;

    int N = in_sizes[0] / D_MODEL;     // 2048 tokens
    int npairs = N * 2;
    int maxblk = (npairs + MT - 1) / MT + NE;   // worst-case padded row-blocks (72)
    int maxrows = maxblk * MT;                  // 4608

    char* ws = (char*)d_ws;
    size_t off = 0;
    auto alloc = [&](size_t bytes) -> void* {
        void* p = ws + off;
        off = (off + bytes + 255) & ~(size_t)255;
        return p;
    };
    int*    topidx  = (int*)   alloc((size_t)npairs * 4);
    float*  topw    = (float*) alloc((size_t)npairs * 4);
    int*    pairTok = (int*)   alloc((size_t)maxrows * 4);
    float*  pairW   = (float*) alloc((size_t)maxrows * 4);
    int*    rbe     = (int*)   alloc((size_t)maxblk * 4);
    __bf16* Xb      = (__bf16*)alloc((size_t)N * D_MODEL * 2);
    __bf16* hidden  = (__bf16*)alloc((size_t)maxrows * D_FF * 2);
    (void)ws_size; (void)n_in;

    hipMemsetAsync(d_out, 0, (size_t)out_size * sizeof(float), stream);
    router_kernel<<<N, 256, 0, stream>>>(x, Wg, bg, topidx, topw, Xb);
    build_lists_kernel<<<1, 256, 0, stream>>>(topidx, topw, pairTok, pairW, rbe,
                                              npairs, maxrows, maxblk);
    gemm1_kernel<<<dim3(maxblk, D_FF / 128), 256, 0, stream>>>(
        Xb, W1, W2, b1, b2, pairTok, rbe, hidden);
    gemm2_kernel<<<dim3(maxblk, D_MODEL / 128), 256, 0, stream>>>(
        hidden, W3, b3, pairTok, pairW, rbe, out);
}

// Round 2
// 496.856 us; speedup vs baseline: 1.4026x; 1.4026x over previous
//
#include <hip/hip_runtime.h>
#include <hip/hip_bf16.h>
#include <math.h>

#define D_MODEL 1024
#define D_FF    4096
#define NE      8
#define MT      64   // row tile (M)
#define BK      32   // K step

typedef __bf16 bf16x8 __attribute__((ext_vector_type(8)));
typedef float  f32x4  __attribute__((ext_vector_type(4)));

// async global -> LDS, 16B per lane. LDS dest is wave-uniform base + lane*16.
__device__ __forceinline__ void async16(const void* g, void* l) {
    __builtin_amdgcn_global_load_lds(
        (__attribute__((address_space(1))) uint32_t*)g,
        (__attribute__((address_space(3))) uint32_t*)l, 16, 0, 0);
}

// ---------------- router: logits, top-2, softmax, x->bf16 ----------------
__global__ __launch_bounds__(256) void router_kernel(
    const float* __restrict__ x, const float* __restrict__ Wg,
    const float* __restrict__ bg, int* __restrict__ topidx,
    float* __restrict__ topw, __bf16* __restrict__ Xb)
{
    int n = blockIdx.x, tid = threadIdx.x;
    const float* xr = x + (size_t)n * D_MODEL;
    int d0 = tid * 4;
    float4 xv = *reinterpret_cast<const float4*>(xr + d0);

    union { __bf16 h[4]; ushort4 u; } pk;
    pk.h[0] = (__bf16)xv.x; pk.h[1] = (__bf16)xv.y;
    pk.h[2] = (__bf16)xv.z; pk.h[3] = (__bf16)xv.w;
    *reinterpret_cast<ushort4*>(Xb + (size_t)n * D_MODEL + d0) = pk.u;

    float part[NE];
#pragma unroll
    for (int e = 0; e < NE; ++e) part[e] = 0.f;
    float xs[4] = {xv.x, xv.y, xv.z, xv.w};
#pragma unroll
    for (int j = 0; j < 4; ++j) {
        const float4* wr = reinterpret_cast<const float4*>(Wg + (size_t)(d0 + j) * NE);
        float4 w0 = wr[0], w1 = wr[1];
        part[0] += xs[j] * w0.x; part[1] += xs[j] * w0.y;
        part[2] += xs[j] * w0.z; part[3] += xs[j] * w0.w;
        part[4] += xs[j] * w1.x; part[5] += xs[j] * w1.y;
        part[6] += xs[j] * w1.z; part[7] += xs[j] * w1.w;
    }
#pragma unroll
    for (int off = 32; off > 0; off >>= 1) {
#pragma unroll
        for (int e = 0; e < NE; ++e) part[e] += __shfl_down(part[e], off);
    }
    __shared__ float sred[4][NE];
    __shared__ float slog[NE];
    int wave = tid >> 6, lane = tid & 63;
    if (lane == 0) {
#pragma unroll
        for (int e = 0; e < NE; ++e) sred[wave][e] = part[e];
    }
    __syncthreads();
    if (tid < NE)
        slog[tid] = bg[tid] + sred[0][tid] + sred[1][tid] + sred[2][tid] + sred[3][tid];
    __syncthreads();
    if (tid == 0) {
        float m0 = -1e30f, m1 = -1e30f; int i0 = 0, i1 = 0;
        for (int e = 0; e < NE; ++e) {
            float l = slog[e];
            if (l > m0)      { m1 = m0; i1 = i0; m0 = l; i0 = e; }
            else if (l > m1) { m1 = l;  i1 = e; }
        }
        float w1 = expf(m1 - m0);
        float s  = 1.f + w1;
        topidx[n * 2 + 0] = i0; topidx[n * 2 + 1] = i1;
        topw[n * 2 + 0] = 1.f / s; topw[n * 2 + 1] = w1 / s;
    }
}

// ---------------- build per-expert padded row lists ----------------
__global__ __launch_bounds__(256) void build_lists_kernel(
    const int* __restrict__ topidx, const float* __restrict__ topw,
    int* __restrict__ pairTok, float* __restrict__ pairW,
    int* __restrict__ rbe, int npairs, int maxrows, int maxblk)
{
    __shared__ int cnt[NE], cur[NE], pof[NE];
    int tid = threadIdx.x;
    if (tid < NE) { cnt[tid] = 0; cur[tid] = 0; }
    for (int i = tid; i < maxrows; i += 256) pairTok[i] = -1;
    for (int i = tid; i < maxblk; i += 256) rbe[i] = -1;
    __syncthreads();
    for (int p = tid; p < npairs; p += 256) atomicAdd(&cnt[topidx[p]], 1);
    __syncthreads();
    if (tid == 0) {
        int off = 0;
        for (int e = 0; e < NE; ++e) { pof[e] = off; off += (cnt[e] + MT - 1) & ~(MT - 1); }
        for (int e = 0; e < NE; ++e) {
            int nb = (cnt[e] + MT - 1) / MT;
            for (int j = 0; j < nb; ++j) rbe[pof[e] / MT + j] = e;
        }
    }
    __syncthreads();
    for (int p = tid; p < npairs; p += 256) {
        int e = topidx[p];
        int pos = atomicAdd(&cur[e], 1);
        int r = pof[e] + pos;
        pairTok[r] = p >> 1;
        pairW[r]   = topw[p];
    }
}

// ---------------- transpose + f32->bf16: src[K][N] -> dst[N][K] ----------------
__global__ __launch_bounds__(256) void transpose_cvt_kernel(
    const float* __restrict__ src, __bf16* __restrict__ dst, int K, int N)
{
    const float* s = src + (size_t)blockIdx.z * K * N;
    __bf16*      d = dst + (size_t)blockIdx.z * K * N;
    int kt = blockIdx.y * 64, nt = blockIdx.x * 64;
    __shared__ float tile[64][65];   // pitch 65: col reads stride 260B -> spread banks
    int tid = threadIdx.x;
    int tr = tid >> 4, tc = (tid & 15) * 4;
#pragma unroll
    for (int it = 0; it < 4; ++it) {
        float4 v = *reinterpret_cast<const float4*>(
            s + (size_t)(kt + tr + it * 16) * N + nt + tc);
        tile[tr + it * 16][tc + 0] = v.x;
        tile[tr + it * 16][tc + 1] = v.y;
        tile[tr + it * 16][tc + 2] = v.z;
        tile[tr + it * 16][tc + 3] = v.w;
    }
    __syncthreads();
    int kq = (tid & 15) * 4;
#pragma unroll
    for (int it = 0; it < 4; ++it) {
        int rr = (tid >> 4) + it * 16;   // n within tile
        union { __bf16 h[4]; ushort4 u; } pk;
        pk.h[0] = (__bf16)tile[kq + 0][rr];
        pk.h[1] = (__bf16)tile[kq + 1][rr];
        pk.h[2] = (__bf16)tile[kq + 2][rr];
        pk.h[3] = (__bf16)tile[kq + 3][rr];
        *reinterpret_cast<ushort4*>(d + (size_t)(nt + rr) * K + kt + kq) = pk.u;
    }
}

// ---------------- GEMM1 (primary): hidden = gelu(X@W1+b1) * (X@W2+b2) ----------------
// W1t/W2t: [e][f][k] bf16, k-contiguous
__global__ __launch_bounds__(256) void gemm1_mfma(
    const __bf16* __restrict__ Xb, const __bf16* __restrict__ W1t,
    const __bf16* __restrict__ W2t, const float* __restrict__ b1,
    const float* __restrict__ b2, const int* __restrict__ pairTok,
    const int* __restrict__ rbe, const __bf16* __restrict__ zpg,
    __bf16* __restrict__ hidden)
{
    int b = blockIdx.x;
    int e = rbe[b];
    if (e < 0) return;
    int fblk = blockIdx.y * 128;

    // per buffer: A[64][32]=2048 | W1[128][32]=4096 | W2[128][32]=4096 elems
    __shared__ __bf16 smem[2][10240];

    int tid = threadIdx.x;
    int ar = tid >> 2;
    int tok = pairTok[b * MT + ar];
    const __bf16* aSrc = (tok >= 0 ? Xb + (size_t)tok * D_MODEL : zpg) + (tid & 3) * 8;
    const __bf16* wbase1 = W1t + ((size_t)e << 22) + (size_t)fblk * D_MODEL;
    const __bf16* wbase2 = W2t + ((size_t)e << 22) + (size_t)fblk * D_MODEL;
    const __bf16* w1s0 = wbase1 + (size_t)(tid >> 2) * D_MODEL + (tid & 3) * 8;
    const __bf16* w1s1 = w1s0 + (size_t)64 * D_MODEL;
    const __bf16* w2s0 = wbase2 + (size_t)(tid >> 2) * D_MODEL + (tid & 3) * 8;
    const __bf16* w2s1 = w2s0 + (size_t)64 * D_MODEL;

    int wave = tid >> 6, lane = tid & 63;
    int wm = (wave >> 1) * 32, wf = (wave & 1) * 64;
    int lm = lane & 15, lk = (lane >> 4) * 8;
    int aoff0 = (wm + lm) * BK + lk;
    int aoff1 = aoff0 + 16 * BK;
    int boff  = (wf + lm) * BK + lk;

    f32x4 c1[2][4], c2[2][4];
#pragma unroll
    for (int mi = 0; mi < 2; ++mi)
#pragma unroll
        for (int fj = 0; fj < 4; ++fj) {
            c1[mi][fj] = (f32x4){0.f, 0.f, 0.f, 0.f};
            c2[mi][fj] = (f32x4){0.f, 0.f, 0.f, 0.f};
        }

    auto stage = [&](int buf, int k0) {
        __bf16* base = &smem[buf][0];
        async16(aSrc + k0, base + tid * 8);
        async16(w1s0 + k0, base + 2048 + tid * 8);
        async16(w1s1 + k0, base + 4096 + tid * 8);
        async16(w2s0 + k0, base + 6144 + tid * 8);
        async16(w2s1 + k0, base + 8192 + tid * 8);
    };

    stage(0, 0);
    __syncthreads();
    const int NT = D_MODEL / BK;
    for (int t = 0; t < NT; ++t) {
        int cur = t & 1;
        if (t + 1 < NT) stage(cur ^ 1, (t + 1) * BK);
        const __bf16* sb = &smem[cur][0];
        bf16x8 a0 = *reinterpret_cast<const bf16x8*>(sb + aoff0);
        bf16x8 a1 = *reinterpret_cast<const bf16x8*>(sb + aoff1);
#pragma unroll
        for (int fj = 0; fj < 4; ++fj) {
            bf16x8 bw1 = *reinterpret_cast<const bf16x8*>(sb + 2048 + boff + fj * 16 * BK);
            bf16x8 bw2 = *reinterpret_cast<const bf16x8*>(sb + 6144 + boff + fj * 16 * BK);
            c1[0][fj] = __builtin_amdgcn_mfma_f32_16x16x32_bf16(a0, bw1, c1[0][fj], 0, 0, 0);
            c1[1][fj] = __builtin_amdgcn_mfma_f32_16x16x32_bf16(a1, bw1, c1[1][fj], 0, 0, 0);
            c2[0][fj] = __builtin_amdgcn_mfma_f32_16x16x32_bf16(a0, bw2, c2[0][fj], 0, 0, 0);
            c2[1][fj] = __builtin_amdgcn_mfma_f32_16x16x32_bf16(a1, bw2, c2[1][fj], 0, 0, 0);
        }
        __syncthreads();
    }

    int r0 = b * MT;
#pragma unroll
    for (int fj = 0; fj < 4; ++fj) {
        int f = fblk + wf + fj * 16 + lm;
        float b1v = b1[e * D_FF + f];
        float b2v = b2[e * D_FF + f];
#pragma unroll
        for (int mi = 0; mi < 2; ++mi)
#pragma unroll
            for (int r = 0; r < 4; ++r) {
                int m = wm + mi * 16 + (lane >> 4) * 4 + r;
                float h1 = c1[mi][fj][r] + b1v;
                float h2 = c2[mi][fj][r] + b2v;
                float g = 0.5f * h1 * (1.f + erff(h1 * 0.70710678118654752f));
                hidden[(size_t)(r0 + m) * D_FF + f] = (__bf16)(g * h2);
            }
    }
}

// ---------------- GEMM2 (primary): out += w * (hidden@W3 + b3) ----------------
// W3t: [e][d][k=f] bf16, k-contiguous
__global__ __launch_bounds__(256) void gemm2_mfma(
    const __bf16* __restrict__ hidden, const __bf16* __restrict__ W3t,
    const float* __restrict__ b3, const int* __restrict__ pairTok,
    const float* __restrict__ pairW, const int* __restrict__ rbe,
    float* __restrict__ out)
{
    int b = blockIdx.x;
    int e = rbe[b];
    if (e < 0) return;
    int dblk = blockIdx.y * 128;

    // per buffer: A[64][32]=2048 | W3[128][32]=4096 elems
    __shared__ __bf16 smem[2][6144];

    int tid = threadIdx.x;
    const __bf16* aSrc = hidden + (size_t)(b * MT + (tid >> 2)) * D_FF + (tid & 3) * 8;
    const __bf16* wbase = W3t + ((size_t)e << 22) + (size_t)dblk * D_FF;
    const __bf16* w3s0 = wbase + (size_t)(tid >> 2) * D_FF + (tid & 3) * 8;
    const __bf16* w3s1 = w3s0 + (size_t)64 * D_FF;

    int wave = tid >> 6, lane = tid & 63;
    int wm = (wave >> 1) * 32, wf = (wave & 1) * 64;
    int lm = lane & 15, lk = (lane >> 4) * 8;
    int aoff0 = (wm + lm) * BK + lk;
    int aoff1 = aoff0 + 16 * BK;
    int boff  = (wf + lm) * BK + lk;

    f32x4 c[2][4];
#pragma unroll
    for (int mi = 0; mi < 2; ++mi)
#pragma unroll
        for (int dj = 0; dj < 4; ++dj) c[mi][dj] = (f32x4){0.f, 0.f, 0.f, 0.f};

    auto stage = [&](int buf, int k0) {
        __bf16* base = &smem[buf][0];
        async16(aSrc + k0, base + tid * 8);
        async16(w3s0 + k0, base + 2048 + tid * 8);
        async16(w3s1 + k0, base + 4096 + tid * 8);
    };

    stage(0, 0);
    __syncthreads();
    const int NT = D_FF / BK;
    for (int t = 0; t < NT; ++t) {
        int cur = t & 1;
        if (t + 1 < NT) stage(cur ^ 1, (t + 1) * BK);
        const __bf16* sb = &smem[cur][0];
        bf16x8 a0 = *reinterpret_cast<const bf16x8*>(sb + aoff0);
        bf16x8 a1 = *reinterpret_cast<const bf16x8*>(sb + aoff1);
#pragma unroll
        for (int dj = 0; dj < 4; ++dj) {
            bf16x8 bw = *reinterpret_cast<const bf16x8*>(sb + 2048 + boff + dj * 16 * BK);
            c[0][dj] = __builtin_amdgcn_mfma_f32_16x16x32_bf16(a0, bw, c[0][dj], 0, 0, 0);
            c[1][dj] = __builtin_amdgcn_mfma_f32_16x16x32_bf16(a1, bw, c[1][dj], 0, 0, 0);
        }
        __syncthreads();
    }

    int r0 = b * MT;
#pragma unroll
    for (int dj = 0; dj < 4; ++dj) {
        int d = dblk + wf + dj * 16 + lm;
        float b3v = b3[e * D_MODEL + d];
#pragma unroll
        for (int mi = 0; mi < 2; ++mi)
#pragma unroll
            for (int r = 0; r < 4; ++r) {
                int m = wm + mi * 16 + (lane >> 4) * 4 + r;
                int gr = r0 + m;
                int tok = pairTok[gr];
                if (tok >= 0) {
                    float val = c[mi][dj][r] + b3v;
                    atomicAdd(out + (size_t)tok * D_MODEL + d, pairW[gr] * val);
                }
            }
    }
}

// ================= legacy fallback (round-1, verified) =================
__global__ __launch_bounds__(256) void gemm1_legacy(
    const __bf16* __restrict__ Xb, const float* __restrict__ W1,
    const float* __restrict__ W2, const float* __restrict__ b1,
    const float* __restrict__ b2, const int* __restrict__ pairTok,
    const int* __restrict__ rbe, __bf16* __restrict__ hidden)
{
    int b = blockIdx.x;
    int e = rbe[b];
    if (e < 0) return;
    int fblk = blockIdx.y * 128;

    __shared__ __bf16 As[64][40];
    __shared__ __bf16 W1s[128][40];
    __shared__ __bf16 W2s[128][40];

    int tid = threadIdx.x;
    int arow = tid >> 2, akoff = (tid & 3) * 8;
    int tok = pairTok[b * MT + arow];
    int wk = tid >> 3, wfb = (tid & 7) * 16;
    const float* w1base = W1 + (size_t)e * D_MODEL * D_FF + (size_t)wk * D_FF + fblk + wfb;
    const float* w2base = W2 + (size_t)e * D_MODEL * D_FF + (size_t)wk * D_FF + fblk + wfb;

    int wave = tid >> 6, lane = tid & 63;
    int wm = (wave >> 1) * 32, wf = (wave & 1) * 64;
    int lm = lane & 15, lk = (lane >> 4) * 8;

    __bf16 z = (__bf16)0.f;
    f32x4 c1[2][4], c2[2][4];
#pragma unroll
    for (int mi = 0; mi < 2; ++mi)
#pragma unroll
        for (int fj = 0; fj < 4; ++fj) {
            c1[mi][fj] = (f32x4){0.f, 0.f, 0.f, 0.f};
            c2[mi][fj] = (f32x4){0.f, 0.f, 0.f, 0.f};
        }

    for (int k0 = 0; k0 < D_MODEL; k0 += BK) {
        __syncthreads();
        bf16x8 av = {z, z, z, z, z, z, z, z};
        if (tok >= 0)
            av = *reinterpret_cast<const bf16x8*>(Xb + (size_t)tok * D_MODEL + k0 + akoff);
        *reinterpret_cast<bf16x8*>(&As[arow][akoff]) = av;
        const float* p1 = w1base + (size_t)k0 * D_FF;
        const float* p2 = w2base + (size_t)k0 * D_FF;
#pragma unroll
        for (int j = 0; j < 4; ++j) {
            float4 v = *reinterpret_cast<const float4*>(p1 + j * 4);
            W1s[wfb + j * 4 + 0][wk] = (__bf16)v.x;
            W1s[wfb + j * 4 + 1][wk] = (__bf16)v.y;
            W1s[wfb + j * 4 + 2][wk] = (__bf16)v.z;
            W1s[wfb + j * 4 + 3][wk] = (__bf16)v.w;
            float4 u = *reinterpret_cast<const float4*>(p2 + j * 4);
            W2s[wfb + j * 4 + 0][wk] = (__bf16)u.x;
            W2s[wfb + j * 4 + 1][wk] = (__bf16)u.y;
            W2s[wfb + j * 4 + 2][wk] = (__bf16)u.z;
            W2s[wfb + j * 4 + 3][wk] = (__bf16)u.w;
        }
        __syncthreads();

        bf16x8 a0 = *reinterpret_cast<bf16x8*>(&As[wm + lm][lk]);
        bf16x8 a1 = *reinterpret_cast<bf16x8*>(&As[wm + 16 + lm][lk]);
#pragma unroll
        for (int fj = 0; fj < 4; ++fj) {
            bf16x8 bw1 = *reinterpret_cast<bf16x8*>(&W1s[wf + fj * 16 + lm][lk]);
            c1[0][fj] = __builtin_amdgcn_mfma_f32_16x16x32_bf16(a0, bw1, c1[0][fj], 0, 0, 0);
            c1[1][fj] = __builtin_amdgcn_mfma_f32_16x16x32_bf16(a1, bw1, c1[1][fj], 0, 0, 0);
            bf16x8 bw2 = *reinterpret_cast<bf16x8*>(&W2s[wf + fj * 16 + lm][lk]);
            c2[0][fj] = __builtin_amdgcn_mfma_f32_16x16x32_bf16(a0, bw2, c2[0][fj], 0, 0, 0);
            c2[1][fj] = __builtin_amdgcn_mfma_f32_16x16x32_bf16(a1, bw2, c2[1][fj], 0, 0, 0);
        }
    }

    int r0 = b * MT;
#pragma unroll
    for (int fj = 0; fj < 4; ++fj) {
        int f = fblk + wf + fj * 16 + lm;
        float b1v = b1[e * D_FF + f];
        float b2v = b2[e * D_FF + f];
#pragma unroll
        for (int mi = 0; mi < 2; ++mi)
#pragma unroll
            for (int r = 0; r < 4; ++r) {
                int m = wm + mi * 16 + (lane >> 4) * 4 + r;
                float h1 = c1[mi][fj][r] + b1v;
                float h2 = c2[mi][fj][r] + b2v;
                float g = 0.5f * h1 * (1.f + erff(h1 * 0.70710678118654752f));
                hidden[(size_t)(r0 + m) * D_FF + f] = (__bf16)(g * h2);
            }
    }
}

__global__ __launch_bounds__(256) void gemm2_legacy(
    const __bf16* __restrict__ hidden, const float* __restrict__ W3,
    const float* __restrict__ b3, const int* __restrict__ pairTok,
    const float* __restrict__ pairW, const int* __restrict__ rbe,
    float* __restrict__ out)
{
    int b = blockIdx.x;
    int e = rbe[b];
    if (e < 0) return;
    int dblk = blockIdx.y * 128;

    __shared__ __bf16 As[64][40];
    __shared__ __bf16 W3s[128][40];

    int tid = threadIdx.x;
    int arow = tid >> 2, akoff = (tid & 3) * 8;
    const __bf16* ap = hidden + (size_t)(b * MT + arow) * D_FF + akoff;
    int wk = tid >> 3, wdb = (tid & 7) * 16;
    const float* w3base = W3 + (size_t)e * D_FF * D_MODEL + (size_t)wk * D_MODEL + dblk + wdb;

    int wave = tid >> 6, lane = tid & 63;
    int wm = (wave >> 1) * 32, wf = (wave & 1) * 64;
    int lm = lane & 15, lk = (lane >> 4) * 8;

    f32x4 c[2][4];
#pragma unroll
    for (int mi = 0; mi < 2; ++mi)
#pragma unroll
        for (int dj = 0; dj < 4; ++dj) c[mi][dj] = (f32x4){0.f, 0.f, 0.f, 0.f};

    for (int k0 = 0; k0 < D_FF; k0 += BK) {
        __syncthreads();
        *reinterpret_cast<bf16x8*>(&As[arow][akoff]) =
            *reinterpret_cast<const bf16x8*>(ap + k0);
        const float* p3 = w3base + (size_t)k0 * D_MODEL;
#pragma unroll
        for (int j = 0; j < 4; ++j) {
            float4 v = *reinterpret_cast<const float4*>(p3 + j * 4);
            W3s[wdb + j * 4 + 0][wk] = (__bf16)v.x;
            W3s[wdb + j * 4 + 1][wk] = (__bf16)v.y;
            W3s[wdb + j * 4 + 2][wk] = (__bf16)v.z;
            W3s[wdb + j * 4 + 3][wk] = (__bf16)v.w;
        }
        __syncthreads();

        bf16x8 a0 = *reinterpret_cast<bf16x8*>(&As[wm + lm][lk]);
        bf16x8 a1 = *reinterpret_cast<bf16x8*>(&As[wm + 16 + lm][lk]);
#pragma unroll
        for (int dj = 0; dj < 4; ++dj) {
            bf16x8 bw = *reinterpret_cast<bf16x8*>(&W3s[wf + dj * 16 + lm][lk]);
            c[0][dj] = __builtin_amdgcn_mfma_f32_16x16x32_bf16(a0, bw, c[0][dj], 0, 0, 0);
            c[1][dj] = __builtin_amdgcn_mfma_f32_16x16x32_bf16(a1, bw, c[1][dj], 0, 0, 0);
        }
    }

    int r0 = b * MT;
#pragma unroll
    for (int dj = 0; dj < 4; ++dj) {
        int d = dblk + wf + dj * 16 + lm;
        float b3v = b3[e * D_MODEL + d];
#pragma unroll
        for (int mi = 0; mi < 2; ++mi)
#pragma unroll
            for (int r = 0; r < 4; ++r) {
                int m = wm + mi * 16 + (lane >> 4) * 4 + r;
                int gr = r0 + m;
                int tok = pairTok[gr];
                if (tok >= 0) {
                    float val = c[mi][dj][r] + b3v;
                    atomicAdd(out + (size_t)tok * D_MODEL + d, pairW[gr] * val);
                }
            }
    }
}

extern "C" void kernel_launch(void* const* d_in, const int* in_sizes, int n_in,
                              void* d_out, int out_size, void* d_ws, size_t ws_size,
                              hipStream_t stream)
{
    const float* x  = (const float*)d_in[0];
    const float* Wg = (const float*)d_in[1];
    const float* bg = (const float*)d_in[2];
    const float* W1 = (const float*)d_in[3];
    const float* b1 = (const float*)d_in[4];
    const float* W2 = (const float*)d_in[5];
    const float* b2 = (const float*)d_in[6];
    const float* W3 = (const float*)d_in[7];
    const float* b3 = (const float*)d_in[8];
    float* out = (float*)d_out;

    int N = in_sizes[0] / D_MODEL;
    int npairs = N * 2;
    int maxblk = (npairs + MT - 1) / MT + NE;
    int maxrows = maxblk * MT;

    char* ws = (char*)d_ws;
    size_t off = 0;
    auto alloc = [&](size_t bytes) -> void* {
        void* p = ws + off;
        off = (off + bytes + 255) & ~(size_t)255;
        return p;
    };
    int*    topidx  = (int*)   alloc((size_t)npairs * 4);
    float*  topw    = (float*) alloc((size_t)npairs * 4);
    int*    pairTok = (int*)   alloc((size_t)maxrows * 4);
    float*  pairW   = (float*) alloc((size_t)maxrows * 4);
    int*    rbe     = (int*)   alloc((size_t)maxblk * 4);
    __bf16* Xb      = (__bf16*)alloc((size_t)N * D_MODEL * 2);
    __bf16* hidden  = (__bf16*)alloc((size_t)maxrows * D_FF * 2);
    __bf16* zpg     = (__bf16*)alloc(2048);
    const size_t WSZ = (size_t)NE * D_MODEL * D_FF * 2;   // 64 MB per matrix
    __bf16* W1t = (__bf16*)alloc(WSZ);
    __bf16* W2t = (__bf16*)alloc(WSZ);
    __bf16* W3t = (__bf16*)alloc(WSZ);
    bool primary = (off <= ws_size);
    (void)n_in;

    hipMemsetAsync(d_out, 0, (size_t)out_size * sizeof(float), stream);
    router_kernel<<<N, 256, 0, stream>>>(x, Wg, bg, topidx, topw, Xb);
    build_lists_kernel<<<1, 256, 0, stream>>>(topidx, topw, pairTok, pairW, rbe,
                                              npairs, maxrows, maxblk);
    if (primary) {
        hipMemsetAsync(zpg, 0, 2048, stream);
        transpose_cvt_kernel<<<dim3(D_FF / 64, D_MODEL / 64, NE), 256, 0, stream>>>(
            W1, W1t, D_MODEL, D_FF);
        transpose_cvt_kernel<<<dim3(D_FF / 64, D_MODEL / 64, NE), 256, 0, stream>>>(
            W2, W2t, D_MODEL, D_FF);
        transpose_cvt_kernel<<<dim3(D_MODEL / 64, D_FF / 64, NE), 256, 0, stream>>>(
            W3, W3t, D_FF, D_MODEL);
        gemm1_mfma<<<dim3(maxblk, D_FF / 128), 256, 0, stream>>>(
            Xb, W1t, W2t, b1, b2, pairTok, rbe, zpg, hidden);
        gemm2_mfma<<<dim3(maxblk, D_MODEL / 128), 256, 0, stream>>>(
            hidden, W3t, b3, pairTok, pairW, rbe, out);
    } else {
        gemm1_legacy<<<dim3(maxblk, D_FF / 128), 256, 0, stream>>>(
            Xb, W1, W2, b1, b2, pairTok, rbe, hidden);
        gemm2_legacy<<<dim3(maxblk, D_MODEL / 128), 256, 0, stream>>>(
            hidden, W3, b3, pairTok, pairW, rbe, out);
    }
}

// Round 4
// 450.594 us; speedup vs baseline: 1.5466x; 1.1027x over previous
//
#include <hip/hip_runtime.h>
#include <hip/hip_bf16.h>
#include <math.h>

#define D_MODEL 1024
#define D_FF    4096
#define NE      8
#define MT      256   // list alignment / M tile
#define BK      64

typedef __bf16 bf16x8 __attribute__((ext_vector_type(8)));
typedef float  f32x4  __attribute__((ext_vector_type(4)));

__device__ __forceinline__ void async16(const void* g, void* l) {
    __builtin_amdgcn_global_load_lds(
        (__attribute__((address_space(1))) uint32_t*)g,
        (__attribute__((address_space(3))) uint32_t*)l, 16, 0, 0);
}

// ---------------- router ----------------
__global__ __launch_bounds__(256) void router_kernel(
    const float* __restrict__ x, const float* __restrict__ Wg,
    const float* __restrict__ bg, int* __restrict__ topidx,
    float* __restrict__ topw, __bf16* __restrict__ Xb)
{
    int n = blockIdx.x, tid = threadIdx.x;
    const float* xr = x + (size_t)n * D_MODEL;
    int d0 = tid * 4;
    float4 xv = *reinterpret_cast<const float4*>(xr + d0);

    union { __bf16 h[4]; ushort4 u; } pk;
    pk.h[0] = (__bf16)xv.x; pk.h[1] = (__bf16)xv.y;
    pk.h[2] = (__bf16)xv.z; pk.h[3] = (__bf16)xv.w;
    *reinterpret_cast<ushort4*>(Xb + (size_t)n * D_MODEL + d0) = pk.u;

    float part[NE];
#pragma unroll
    for (int e = 0; e < NE; ++e) part[e] = 0.f;
    float xs[4] = {xv.x, xv.y, xv.z, xv.w};
#pragma unroll
    for (int j = 0; j < 4; ++j) {
        const float4* wr = reinterpret_cast<const float4*>(Wg + (size_t)(d0 + j) * NE);
        float4 w0 = wr[0], w1 = wr[1];
        part[0] += xs[j] * w0.x; part[1] += xs[j] * w0.y;
        part[2] += xs[j] * w0.z; part[3] += xs[j] * w0.w;
        part[4] += xs[j] * w1.x; part[5] += xs[j] * w1.y;
        part[6] += xs[j] * w1.z; part[7] += xs[j] * w1.w;
    }
#pragma unroll
    for (int off = 32; off > 0; off >>= 1) {
#pragma unroll
        for (int e = 0; e < NE; ++e) part[e] += __shfl_down(part[e], off);
    }
    __shared__ float sred[4][NE];
    __shared__ float slog[NE];
    int wave = tid >> 6, lane = tid & 63;
    if (lane == 0) {
#pragma unroll
        for (int e = 0; e < NE; ++e) sred[wave][e] = part[e];
    }
    __syncthreads();
    if (tid < NE)
        slog[tid] = bg[tid] + sred[0][tid] + sred[1][tid] + sred[2][tid] + sred[3][tid];
    __syncthreads();
    if (tid == 0) {
        float m0 = -1e30f, m1 = -1e30f; int i0 = 0, i1 = 0;
        for (int e = 0; e < NE; ++e) {
            float l = slog[e];
            if (l > m0)      { m1 = m0; i1 = i0; m0 = l; i0 = e; }
            else if (l > m1) { m1 = l;  i1 = e; }
        }
        float w1 = expf(m1 - m0);
        float s  = 1.f + w1;
        topidx[n * 2 + 0] = i0; topidx[n * 2 + 1] = i1;
        topw[n * 2 + 0] = 1.f / s; topw[n * 2 + 1] = w1 / s;
    }
}

// ---------------- build per-expert padded row lists (align 256) ----------------
__global__ __launch_bounds__(256) void build_lists_kernel(
    const int* __restrict__ topidx, const float* __restrict__ topw,
    int* __restrict__ pairTok, float* __restrict__ pairW,
    int* __restrict__ rbe, int npairs, int maxrows, int maxblk)
{
    __shared__ int cnt[NE], cur[NE], pof[NE];
    int tid = threadIdx.x;
    if (tid < NE) { cnt[tid] = 0; cur[tid] = 0; }
    for (int i = tid; i < maxrows; i += 256) pairTok[i] = -1;
    for (int i = tid; i < maxblk; i += 256) rbe[i] = -1;
    __syncthreads();
    for (int p = tid; p < npairs; p += 256) atomicAdd(&cnt[topidx[p]], 1);
    __syncthreads();
    if (tid == 0) {
        int off = 0;
        for (int e = 0; e < NE; ++e) { pof[e] = off; off += (cnt[e] + MT - 1) & ~(MT - 1); }
        for (int e = 0; e < NE; ++e) {
            int nb = (cnt[e] + MT - 1) / MT;
            for (int j = 0; j < nb; ++j) rbe[pof[e] / MT + j] = e;
        }
    }
    __syncthreads();
    for (int p = tid; p < npairs; p += 256) {
        int e = topidx[p];
        int pos = atomicAdd(&cur[e], 1);
        int r = pof[e] + pos;
        pairTok[r] = p >> 1;
        pairW[r]   = topw[p];
    }
}

// ---------------- transpose + f32->bf16: src[K][N] -> dst[N][K] ----------------
__global__ __launch_bounds__(256) void transpose_cvt_kernel(
    const float* __restrict__ src, __bf16* __restrict__ dst, int K, int N)
{
    const float* s = src + (size_t)blockIdx.z * K * N;
    __bf16*      d = dst + (size_t)blockIdx.z * K * N;
    int kt = blockIdx.y * 64, nt = blockIdx.x * 64;
    __shared__ float tile[64][65];
    int tid = threadIdx.x;
    int tr = tid >> 4, tc = (tid & 15) * 4;
#pragma unroll
    for (int it = 0; it < 4; ++it) {
        float4 v = *reinterpret_cast<const float4*>(
            s + (size_t)(kt + tr + it * 16) * N + nt + tc);
        tile[tr + it * 16][tc + 0] = v.x;
        tile[tr + it * 16][tc + 1] = v.y;
        tile[tr + it * 16][tc + 2] = v.z;
        tile[tr + it * 16][tc + 3] = v.w;
    }
    __syncthreads();
    int kq = (tid & 15) * 4;
#pragma unroll
    for (int it = 0; it < 4; ++it) {
        int rr = (tid >> 4) + it * 16;
        union { __bf16 h[4]; ushort4 u; } pk;
        pk.h[0] = (__bf16)tile[kq + 0][rr];
        pk.h[1] = (__bf16)tile[kq + 1][rr];
        pk.h[2] = (__bf16)tile[kq + 2][rr];
        pk.h[3] = (__bf16)tile[kq + 3][rr];
        *reinterpret_cast<ushort4*>(d + (size_t)(nt + rr) * K + kt + kq) = pk.u;
    }
}

// ---------------- GEMM1: 256x128 dual-B, BK=64, 512 threads (8 waves) ----------------
// LDS elems/buf: A[256*64]=16384 @0 | B1[128*64]=8192 @16384 | B2 @24576 -> 64KB, x2 dbuf
// Coverage audit: A 8w*4instr*8rows=256 | B1 8w*2*8=128 | B2 128. Compute: 8 waves x
// (64m x 64f) at wm=(w>>1)*64 (0..192), wf=(w&1)*64 (0,64) = 256x128.
__global__ __launch_bounds__(512) void gemm1_mfma(
    const __bf16* __restrict__ Xb, const __bf16* __restrict__ W1t,
    const __bf16* __restrict__ W2t, const float* __restrict__ b1,
    const float* __restrict__ b2, const int* __restrict__ pairTok,
    const int* __restrict__ rbe, const __bf16* __restrict__ zpg,
    __bf16* __restrict__ hidden)
{
    int b = blockIdx.x;
    int e = rbe[b];
    if (e < 0) return;
    int fblk = blockIdx.y * 128;

    __shared__ __bf16 smem[2][32768];

    int tid = threadIdx.x, w = tid >> 6, l = tid & 63;
    int srcslot = (l & 7) ^ (l >> 3);   // swizzle: LDS[row][slot] = src[row][slot ^ (row&7)]
    int r0 = b * MT;

    const __bf16* aptr[4];
#pragma unroll
    for (int j = 0; j < 4; ++j) {
        int row = w * 32 + j * 8 + (l >> 3);
        int tok = pairTok[r0 + row];
        aptr[j] = (tok >= 0 ? Xb + (size_t)tok * D_MODEL : zpg) + srcslot * 8;
    }
    const __bf16* b1base = W1t + ((size_t)e << 22)
        + (size_t)(fblk + w * 16 + (l >> 3)) * D_MODEL + srcslot * 8;
    const __bf16* b2base = W2t + ((size_t)e << 22)
        + (size_t)(fblk + w * 16 + (l >> 3)) * D_MODEL + srcslot * 8;

    int wm = (w >> 1) * 64, wf = (w & 1) * 64;
    int lm = l & 15;

    f32x4 c1[4][4], c2[4][4];
#pragma unroll
    for (int mi = 0; mi < 4; ++mi)
#pragma unroll
        for (int fj = 0; fj < 4; ++fj) {
            c1[mi][fj] = (f32x4){0.f, 0.f, 0.f, 0.f};
            c2[mi][fj] = (f32x4){0.f, 0.f, 0.f, 0.f};
        }

    auto stage = [&](int buf, int k0) {
        __bf16* base = &smem[buf][0];
#pragma unroll
        for (int j = 0; j < 4; ++j)
            async16(aptr[j] + k0, base + w * 2048 + j * 512);
        async16(b1base + k0,               base + 16384 + w * 1024);
        async16(b1base + 8 * D_MODEL + k0, base + 16384 + w * 1024 + 512);
        async16(b2base + k0,               base + 24576 + w * 1024);
        async16(b2base + 8 * D_MODEL + k0, base + 24576 + w * 1024 + 512);
    };

    stage(0, 0);
    __syncthreads();
    const int NT = D_MODEL / BK;   // 16
    for (int t = 0; t < NT; ++t) {
        int cur = t & 1;
        if (t + 1 < NT) stage(cur ^ 1, (t + 1) * BK);
        const __bf16* sb = &smem[cur][0];
#pragma unroll
        for (int ks = 0; ks < 2; ++ks) {
            int sl = (((ks * 4 + (l >> 4)) ^ (l & 7)) << 3);   // read XOR = row&7 = l&7
            bf16x8 a[4];
#pragma unroll
            for (int mi = 0; mi < 4; ++mi)
                a[mi] = *reinterpret_cast<const bf16x8*>(sb + (wm + mi * 16 + lm) * 64 + sl);
#pragma unroll
            for (int fj = 0; fj < 4; ++fj) {
                int frow = wf + fj * 16 + lm;
                bf16x8 bv1 = *reinterpret_cast<const bf16x8*>(sb + 16384 + frow * 64 + sl);
                bf16x8 bv2 = *reinterpret_cast<const bf16x8*>(sb + 24576 + frow * 64 + sl);
#pragma unroll
                for (int mi = 0; mi < 4; ++mi) {
                    c1[mi][fj] = __builtin_amdgcn_mfma_f32_16x16x32_bf16(a[mi], bv1, c1[mi][fj], 0, 0, 0);
                    c2[mi][fj] = __builtin_amdgcn_mfma_f32_16x16x32_bf16(a[mi], bv2, c2[mi][fj], 0, 0, 0);
                }
            }
        }
        __syncthreads();
    }

#pragma unroll
    for (int fj = 0; fj < 4; ++fj) {
        int f = fblk + wf + fj * 16 + lm;
        float b1v = b1[e * D_FF + f];
        float b2v = b2[e * D_FF + f];
#pragma unroll
        for (int mi = 0; mi < 4; ++mi)
#pragma unroll
            for (int r = 0; r < 4; ++r) {
                int m = wm + mi * 16 + (l >> 4) * 4 + r;
                float h1 = c1[mi][fj][r] + b1v;
                float h2 = c2[mi][fj][r] + b2v;
                float g = 0.5f * h1 * (1.f + erff(h1 * 0.70710678118654752f));
                hidden[(size_t)(r0 + m) * D_FF + f] = (__bf16)(g * h2);
            }
    }
}

// ---------------- GEMM2: 256x256, BK=64, splitK=3, 512 threads (8 waves) ----------------
// LDS elems/buf: A[256*64]=16384 @0 | B[256*64]=16384 @16384 -> 64KB, x2 dbuf
// Coverage: A 8w*4*8=256 | B 8w*4*8=256. Compute: 8 waves x (128m x 64n) at
// wm=(w>>2)*128 (0,128), wn=(w&3)*64 (0..192) = 256x256.
__global__ __launch_bounds__(512) void gemm2_mfma(
    const __bf16* __restrict__ hidden, const __bf16* __restrict__ W3t,
    const float* __restrict__ b3, const int* __restrict__ pairTok,
    const float* __restrict__ pairW, const int* __restrict__ rbe,
    float* __restrict__ out)
{
    int b = blockIdx.x;
    int e = rbe[b];
    if (e < 0) return;
    int dblk = blockIdx.y * 256;
    int split = blockIdx.z;

    __shared__ __bf16 smem[2][32768];

    int tid = threadIdx.x, w = tid >> 6, l = tid & 63;
    int srcslot = (l & 7) ^ (l >> 3);
    int r0 = b * MT;

    const __bf16* abase = hidden + (size_t)(r0 + w * 32 + (l >> 3)) * D_FF + srcslot * 8;
    const __bf16* bbase = W3t + ((size_t)e << 22)
        + (size_t)(dblk + w * 32 + (l >> 3)) * D_FF + srcslot * 8;

    int wm = (w >> 2) * 128, wn = (w & 3) * 64;
    int lm = l & 15;

    f32x4 c[8][4];
#pragma unroll
    for (int mi = 0; mi < 8; ++mi)
#pragma unroll
        for (int nj = 0; nj < 4; ++nj) c[mi][nj] = (f32x4){0.f, 0.f, 0.f, 0.f};

    auto stage = [&](int buf, int k0) {
        __bf16* base = &smem[buf][0];
#pragma unroll
        for (int j = 0; j < 4; ++j)
            async16(abase + (size_t)j * 8 * D_FF + k0, base + w * 2048 + j * 512);
#pragma unroll
        for (int j = 0; j < 4; ++j)
            async16(bbase + (size_t)j * 8 * D_FF + k0, base + 16384 + w * 2048 + j * 512);
    };

    const int NTtot = D_FF / BK;         // 64
    int tbeg = split * 22;
    int tend = min(NTtot, tbeg + 22);    // 22/22/20

    stage(0, tbeg * BK);
    __syncthreads();
    for (int t = tbeg; t < tend; ++t) {
        int cur = (t - tbeg) & 1;
        if (t + 1 < tend) stage(cur ^ 1, (t + 1) * BK);
        const __bf16* sb = &smem[cur][0];
#pragma unroll
        for (int ks = 0; ks < 2; ++ks) {
            int sl = (((ks * 4 + (l >> 4)) ^ (l & 7)) << 3);
            bf16x8 a[8];
#pragma unroll
            for (int mi = 0; mi < 8; ++mi)
                a[mi] = *reinterpret_cast<const bf16x8*>(sb + (wm + mi * 16 + lm) * 64 + sl);
#pragma unroll
            for (int nj = 0; nj < 4; ++nj) {
                bf16x8 bv = *reinterpret_cast<const bf16x8*>(sb + 16384 + (wn + nj * 16 + lm) * 64 + sl);
#pragma unroll
                for (int mi = 0; mi < 8; ++mi)
                    c[mi][nj] = __builtin_amdgcn_mfma_f32_16x16x32_bf16(a[mi], bv, c[mi][nj], 0, 0, 0);
            }
        }
        __syncthreads();
    }

#pragma unroll
    for (int nj = 0; nj < 4; ++nj) {
        int d = dblk + wn + nj * 16 + lm;
        float b3v = (split == 0) ? b3[e * D_MODEL + d] : 0.f;
#pragma unroll
        for (int mi = 0; mi < 8; ++mi)
#pragma unroll
            for (int r = 0; r < 4; ++r) {
                int m = wm + mi * 16 + (l >> 4) * 4 + r;
                int gr = r0 + m;
                int tok = pairTok[gr];
                if (tok >= 0) {
                    float val = c[mi][nj][r] + b3v;
                    atomicAdd(out + (size_t)tok * D_MODEL + d, pairW[gr] * val);
                }
            }
    }
}

// ================= legacy fallback (64-row blocks on 256-aligned lists) =================
__global__ __launch_bounds__(256) void gemm1_legacy(
    const __bf16* __restrict__ Xb, const float* __restrict__ W1,
    const float* __restrict__ W2, const float* __restrict__ b1,
    const float* __restrict__ b2, const int* __restrict__ pairTok,
    const int* __restrict__ rbe, __bf16* __restrict__ hidden)
{
    int b = blockIdx.x;
    int e = rbe[b >> 2];
    if (e < 0) return;
    int fblk = blockIdx.y * 128;

    __shared__ __bf16 As[64][40];
    __shared__ __bf16 W1s[128][40];
    __shared__ __bf16 W2s[128][40];

    int tid = threadIdx.x;
    int arow = tid >> 2, akoff = (tid & 3) * 8;
    int r0 = b * 64;
    int tok = pairTok[r0 + arow];
    int wk = tid >> 3, wfb = (tid & 7) * 16;
    const float* w1base = W1 + (size_t)e * D_MODEL * D_FF + (size_t)wk * D_FF + fblk + wfb;
    const float* w2base = W2 + (size_t)e * D_MODEL * D_FF + (size_t)wk * D_FF + fblk + wfb;

    int wave = tid >> 6, lane = tid & 63;
    int wm = (wave >> 1) * 32, wf = (wave & 1) * 64;
    int lm = lane & 15, lk = (lane >> 4) * 8;

    __bf16 z = (__bf16)0.f;
    f32x4 c1[2][4], c2[2][4];
#pragma unroll
    for (int mi = 0; mi < 2; ++mi)
#pragma unroll
        for (int fj = 0; fj < 4; ++fj) {
            c1[mi][fj] = (f32x4){0.f, 0.f, 0.f, 0.f};
            c2[mi][fj] = (f32x4){0.f, 0.f, 0.f, 0.f};
        }

    for (int k0 = 0; k0 < D_MODEL; k0 += 32) {
        __syncthreads();
        bf16x8 av = {z, z, z, z, z, z, z, z};
        if (tok >= 0)
            av = *reinterpret_cast<const bf16x8*>(Xb + (size_t)tok * D_MODEL + k0 + akoff);
        *reinterpret_cast<bf16x8*>(&As[arow][akoff]) = av;
        const float* p1 = w1base + (size_t)k0 * D_FF;
        const float* p2 = w2base + (size_t)k0 * D_FF;
#pragma unroll
        for (int j = 0; j < 4; ++j) {
            float4 v = *reinterpret_cast<const float4*>(p1 + j * 4);
            W1s[wfb + j * 4 + 0][wk] = (__bf16)v.x;
            W1s[wfb + j * 4 + 1][wk] = (__bf16)v.y;
            W1s[wfb + j * 4 + 2][wk] = (__bf16)v.z;
            W1s[wfb + j * 4 + 3][wk] = (__bf16)v.w;
            float4 u = *reinterpret_cast<const float4*>(p2 + j * 4);
            W2s[wfb + j * 4 + 0][wk] = (__bf16)u.x;
            W2s[wfb + j * 4 + 1][wk] = (__bf16)u.y;
            W2s[wfb + j * 4 + 2][wk] = (__bf16)u.z;
            W2s[wfb + j * 4 + 3][wk] = (__bf16)u.w;
        }
        __syncthreads();

        bf16x8 a0 = *reinterpret_cast<bf16x8*>(&As[wm + lm][lk]);
        bf16x8 a1 = *reinterpret_cast<bf16x8*>(&As[wm + 16 + lm][lk]);
#pragma unroll
        for (int fj = 0; fj < 4; ++fj) {
            bf16x8 bw1 = *reinterpret_cast<bf16x8*>(&W1s[wf + fj * 16 + lm][lk]);
            c1[0][fj] = __builtin_amdgcn_mfma_f32_16x16x32_bf16(a0, bw1, c1[0][fj], 0, 0, 0);
            c1[1][fj] = __builtin_amdgcn_mfma_f32_16x16x32_bf16(a1, bw1, c1[1][fj], 0, 0, 0);
            bf16x8 bw2 = *reinterpret_cast<bf16x8*>(&W2s[wf + fj * 16 + lm][lk]);
            c2[0][fj] = __builtin_amdgcn_mfma_f32_16x16x32_bf16(a0, bw2, c2[0][fj], 0, 0, 0);
            c2[1][fj] = __builtin_amdgcn_mfma_f32_16x16x32_bf16(a1, bw2, c2[1][fj], 0, 0, 0);
        }
    }

#pragma unroll
    for (int fj = 0; fj < 4; ++fj) {
        int f = fblk + wf + fj * 16 + lm;
        float b1v = b1[e * D_FF + f];
        float b2v = b2[e * D_FF + f];
#pragma unroll
        for (int mi = 0; mi < 2; ++mi)
#pragma unroll
            for (int r = 0; r < 4; ++r) {
                int m = wm + mi * 16 + (lane >> 4) * 4 + r;
                float h1 = c1[mi][fj][r] + b1v;
                float h2 = c2[mi][fj][r] + b2v;
                float g = 0.5f * h1 * (1.f + erff(h1 * 0.70710678118654752f));
                hidden[(size_t)(r0 + m) * D_FF + f] = (__bf16)(g * h2);
            }
    }
}

__global__ __launch_bounds__(256) void gemm2_legacy(
    const __bf16* __restrict__ hidden, const float* __restrict__ W3,
    const float* __restrict__ b3, const int* __restrict__ pairTok,
    const float* __restrict__ pairW, const int* __restrict__ rbe,
    float* __restrict__ out)
{
    int b = blockIdx.x;
    int e = rbe[b >> 2];
    if (e < 0) return;
    int dblk = blockIdx.y * 128;

    __shared__ __bf16 As[64][40];
    __shared__ __bf16 W3s[128][40];

    int tid = threadIdx.x;
    int arow = tid >> 2, akoff = (tid & 3) * 8;
    int r0 = b * 64;
    const __bf16* ap = hidden + (size_t)(r0 + arow) * D_FF + akoff;
    int wk = tid >> 3, wdb = (tid & 7) * 16;
    const float* w3base = W3 + (size_t)e * D_FF * D_MODEL + (size_t)wk * D_MODEL + dblk + wdb;

    int wave = tid >> 6, lane = tid & 63;
    int wm = (wave >> 1) * 32, wf = (wave & 1) * 64;
    int lm = lane & 15, lk = (lane >> 4) * 8;

    f32x4 c[2][4];
#pragma unroll
    for (int mi = 0; mi < 2; ++mi)
#pragma unroll
        for (int dj = 0; dj < 4; ++dj) c[mi][dj] = (f32x4){0.f, 0.f, 0.f, 0.f};

    for (int k0 = 0; k0 < D_FF; k0 += 32) {
        __syncthreads();
        *reinterpret_cast<bf16x8*>(&As[arow][akoff]) =
            *reinterpret_cast<const bf16x8*>(ap + k0);
        const float* p3 = w3base + (size_t)k0 * D_MODEL;
#pragma unroll
        for (int j = 0; j < 4; ++j) {
            float4 v = *reinterpret_cast<const float4*>(p3 + j * 4);
            W3s[wdb + j * 4 + 0][wk] = (__bf16)v.x;
            W3s[wdb + j * 4 + 1][wk] = (__bf16)v.y;
            W3s[wdb + j * 4 + 2][wk] = (__bf16)v.z;
            W3s[wdb + j * 4 + 3][wk] = (__bf16)v.w;
        }
        __syncthreads();

        bf16x8 a0 = *reinterpret_cast<bf16x8*>(&As[wm + lm][lk]);
        bf16x8 a1 = *reinterpret_cast<bf16x8*>(&As[wm + 16 + lm][lk]);
#pragma unroll
        for (int dj = 0; dj < 4; ++dj) {
            bf16x8 bw = *reinterpret_cast<bf16x8*>(&W3s[wf + dj * 16 + lm][lk]);
            c[0][dj] = __builtin_amdgcn_mfma_f32_16x16x32_bf16(a0, bw, c[0][dj], 0, 0, 0);
            c[1][dj] = __builtin_amdgcn_mfma_f32_16x16x32_bf16(a1, bw, c[1][dj], 0, 0, 0);
        }
    }

#pragma unroll
    for (int dj = 0; dj < 4; ++dj) {
        int d = dblk + wf + dj * 16 + lm;
        float b3v = b3[e * D_MODEL + d];
#pragma unroll
        for (int mi = 0; mi < 2; ++mi)
#pragma unroll
            for (int r = 0; r < 4; ++r) {
                int m = wm + mi * 16 + (lane >> 4) * 4 + r;
                int gr = r0 + m;
                int tok = pairTok[gr];
                if (tok >= 0) {
                    float val = c[mi][dj][r] + b3v;
                    atomicAdd(out + (size_t)tok * D_MODEL + d, pairW[gr] * val);
                }
            }
    }
}

extern "C" void kernel_launch(void* const* d_in, const int* in_sizes, int n_in,
                              void* d_out, int out_size, void* d_ws, size_t ws_size,
                              hipStream_t stream)
{
    const float* x  = (const float*)d_in[0];
    const float* Wg = (const float*)d_in[1];
    const float* bg = (const float*)d_in[2];
    const float* W1 = (const float*)d_in[3];
    const float* b1 = (const float*)d_in[4];
    const float* W2 = (const float*)d_in[5];
    const float* b2 = (const float*)d_in[6];
    const float* W3 = (const float*)d_in[7];
    const float* b3 = (const float*)d_in[8];
    float* out = (float*)d_out;

    int N = in_sizes[0] / D_MODEL;
    int npairs = N * 2;
    int maxblk = npairs / MT + NE;     // 24
    int maxrows = maxblk * MT;         // 6144

    char* ws = (char*)d_ws;
    size_t off = 0;
    auto alloc = [&](size_t bytes) -> void* {
        void* p = ws + off;
        off = (off + bytes + 255) & ~(size_t)255;
        return p;
    };
    int*    topidx  = (int*)   alloc((size_t)npairs * 4);
    float*  topw    = (float*) alloc((size_t)npairs * 4);
    int*    pairTok = (int*)   alloc((size_t)maxrows * 4);
    float*  pairW   = (float*) alloc((size_t)maxrows * 4);
    int*    rbe     = (int*)   alloc((size_t)maxblk * 4);
    __bf16* Xb      = (__bf16*)alloc((size_t)N * D_MODEL * 2);
    __bf16* hidden  = (__bf16*)alloc((size_t)maxrows * D_FF * 2);
    __bf16* zpg     = (__bf16*)alloc(4096);
    const size_t WSZ = (size_t)NE * D_MODEL * D_FF * 2;   // 64 MB per matrix
    __bf16* W1t = (__bf16*)alloc(WSZ);
    __bf16* W2t = (__bf16*)alloc(WSZ);
    __bf16* W3t = (__bf16*)alloc(WSZ);
    bool primary = (off <= ws_size);
    (void)n_in;

    hipMemsetAsync(d_out, 0, (size_t)out_size * sizeof(float), stream);
    router_kernel<<<N, 256, 0, stream>>>(x, Wg, bg, topidx, topw, Xb);
    build_lists_kernel<<<1, 256, 0, stream>>>(topidx, topw, pairTok, pairW, rbe,
                                              npairs, maxrows, maxblk);
    if (primary) {
        hipMemsetAsync(zpg, 0, 4096, stream);
        transpose_cvt_kernel<<<dim3(D_FF / 64, D_MODEL / 64, NE), 256, 0, stream>>>(
            W1, W1t, D_MODEL, D_FF);
        transpose_cvt_kernel<<<dim3(D_FF / 64, D_MODEL / 64, NE), 256, 0, stream>>>(
            W2, W2t, D_MODEL, D_FF);
        transpose_cvt_kernel<<<dim3(D_MODEL / 64, D_FF / 64, NE), 256, 0, stream>>>(
            W3, W3t, D_FF, D_MODEL);
        gemm1_mfma<<<dim3(maxblk, D_FF / 128), 512, 0, stream>>>(
            Xb, W1t, W2t, b1, b2, pairTok, rbe, zpg, hidden);
        gemm2_mfma<<<dim3(maxblk, D_MODEL / 256, 3), 512, 0, stream>>>(
            hidden, W3t, b3, pairTok, pairW, rbe, out);
    } else {
        gemm1_legacy<<<dim3(maxblk * 4, D_FF / 128), 256, 0, stream>>>(
            Xb, W1, W2, b1, b2, pairTok, rbe, hidden);
        gemm2_legacy<<<dim3(maxblk * 4, D_MODEL / 128), 256, 0, stream>>>(
            hidden, W3, b3, pairTok, pairW, rbe, out);
    }
}

// Round 5
// 347.000 us; speedup vs baseline: 2.0083x; 1.2985x over previous
//
#include <hip/hip_runtime.h>
#include <hip/hip_bf16.h>
#include <math.h>

#define D_MODEL 1024
#define D_FF    4096
#define NE      8
#define MT      256   // list alignment (gemm1 M tile)

typedef __bf16 bf16x8 __attribute__((ext_vector_type(8)));
typedef float  f32x4  __attribute__((ext_vector_type(4)));

__device__ __forceinline__ void async16(const void* g, void* l) {
    __builtin_amdgcn_global_load_lds(
        (__attribute__((address_space(1))) uint32_t*)g,
        (__attribute__((address_space(3))) uint32_t*)l, 16, 0, 0);
}

// ---------------- router ----------------
__global__ __launch_bounds__(256) void router_kernel(
    const float* __restrict__ x, const float* __restrict__ Wg,
    const float* __restrict__ bg, int* __restrict__ topidx,
    float* __restrict__ topw, __bf16* __restrict__ Xb)
{
    int n = blockIdx.x, tid = threadIdx.x;
    const float* xr = x + (size_t)n * D_MODEL;
    int d0 = tid * 4;
    float4 xv = *reinterpret_cast<const float4*>(xr + d0);

    union { __bf16 h[4]; ushort4 u; } pk;
    pk.h[0] = (__bf16)xv.x; pk.h[1] = (__bf16)xv.y;
    pk.h[2] = (__bf16)xv.z; pk.h[3] = (__bf16)xv.w;
    *reinterpret_cast<ushort4*>(Xb + (size_t)n * D_MODEL + d0) = pk.u;

    float part[NE];
#pragma unroll
    for (int e = 0; e < NE; ++e) part[e] = 0.f;
    float xs[4] = {xv.x, xv.y, xv.z, xv.w};
#pragma unroll
    for (int j = 0; j < 4; ++j) {
        const float4* wr = reinterpret_cast<const float4*>(Wg + (size_t)(d0 + j) * NE);
        float4 w0 = wr[0], w1 = wr[1];
        part[0] += xs[j] * w0.x; part[1] += xs[j] * w0.y;
        part[2] += xs[j] * w0.z; part[3] += xs[j] * w0.w;
        part[4] += xs[j] * w1.x; part[5] += xs[j] * w1.y;
        part[6] += xs[j] * w1.z; part[7] += xs[j] * w1.w;
    }
#pragma unroll
    for (int off = 32; off > 0; off >>= 1) {
#pragma unroll
        for (int e = 0; e < NE; ++e) part[e] += __shfl_down(part[e], off);
    }
    __shared__ float sred[4][NE];
    __shared__ float slog[NE];
    int wave = tid >> 6, lane = tid & 63;
    if (lane == 0) {
#pragma unroll
        for (int e = 0; e < NE; ++e) sred[wave][e] = part[e];
    }
    __syncthreads();
    if (tid < NE)
        slog[tid] = bg[tid] + sred[0][tid] + sred[1][tid] + sred[2][tid] + sred[3][tid];
    __syncthreads();
    if (tid == 0) {
        float m0 = -1e30f, m1 = -1e30f; int i0 = 0, i1 = 0;
        for (int e = 0; e < NE; ++e) {
            float l = slog[e];
            if (l > m0)      { m1 = m0; i1 = i0; m0 = l; i0 = e; }
            else if (l > m1) { m1 = l;  i1 = e; }
        }
        float w1 = expf(m1 - m0);
        float s  = 1.f + w1;
        topidx[n * 2 + 0] = i0; topidx[n * 2 + 1] = i1;
        topw[n * 2 + 0] = 1.f / s; topw[n * 2 + 1] = w1 / s;
    }
}

// ---------------- build per-expert padded row lists (align 256) + pairRow ----------------
__global__ __launch_bounds__(256) void build_lists_kernel(
    const int* __restrict__ topidx, const float* __restrict__ topw,
    int* __restrict__ pairTok, float* __restrict__ pairW,
    int* __restrict__ rbe, int* __restrict__ pairRow,
    int npairs, int maxrows, int maxblk)
{
    __shared__ int cnt[NE], cur[NE], pof[NE];
    int tid = threadIdx.x;
    if (tid < NE) { cnt[tid] = 0; cur[tid] = 0; }
    for (int i = tid; i < maxrows; i += 256) pairTok[i] = -1;
    for (int i = tid; i < maxblk; i += 256) rbe[i] = -1;
    __syncthreads();
    for (int p = tid; p < npairs; p += 256) atomicAdd(&cnt[topidx[p]], 1);
    __syncthreads();
    if (tid == 0) {
        int off = 0;
        for (int e = 0; e < NE; ++e) { pof[e] = off; off += (cnt[e] + MT - 1) & ~(MT - 1); }
        for (int e = 0; e < NE; ++e) {
            int nb = (cnt[e] + MT - 1) / MT;
            for (int j = 0; j < nb; ++j) rbe[pof[e] / MT + j] = e;
        }
    }
    __syncthreads();
    for (int p = tid; p < npairs; p += 256) {
        int e = topidx[p];
        int pos = atomicAdd(&cur[e], 1);
        int r = pof[e] + pos;
        pairTok[r]  = p >> 1;
        pairW[r]    = topw[p];
        pairRow[p]  = r;
    }
}

// ---------------- transpose + f32->bf16: src[K][N] -> dst[N][K] ----------------
__global__ __launch_bounds__(256) void transpose_cvt_kernel(
    const float* __restrict__ src, __bf16* __restrict__ dst, int K, int N)
{
    const float* s = src + (size_t)blockIdx.z * K * N;
    __bf16*      d = dst + (size_t)blockIdx.z * K * N;
    int kt = blockIdx.y * 64, nt = blockIdx.x * 64;
    __shared__ float tile[64][65];
    int tid = threadIdx.x;
    int tr = tid >> 4, tc = (tid & 15) * 4;
#pragma unroll
    for (int it = 0; it < 4; ++it) {
        float4 v = *reinterpret_cast<const float4*>(
            s + (size_t)(kt + tr + it * 16) * N + nt + tc);
        tile[tr + it * 16][tc + 0] = v.x;
        tile[tr + it * 16][tc + 1] = v.y;
        tile[tr + it * 16][tc + 2] = v.z;
        tile[tr + it * 16][tc + 3] = v.w;
    }
    __syncthreads();
    int kq = (tid & 15) * 4;
#pragma unroll
    for (int it = 0; it < 4; ++it) {
        int rr = (tid >> 4) + it * 16;
        union { __bf16 h[4]; ushort4 u; } pk;
        pk.h[0] = (__bf16)tile[kq + 0][rr];
        pk.h[1] = (__bf16)tile[kq + 1][rr];
        pk.h[2] = (__bf16)tile[kq + 2][rr];
        pk.h[3] = (__bf16)tile[kq + 3][rr];
        *reinterpret_cast<ushort4*>(d + (size_t)(nt + rr) * K + kt + kq) = pk.u;
    }
}

// ---------------- GEMM1: 256x64 dual-B, BK=32, 512 thr, 48KB LDS (2 blk/CU) ----------------
// LDS elems/buf: A[256*32]=8192 @0 | B1[64*32]=2048 @8192 | B2 @10240 = 12288 (24KB)
// Coverage: A 8w*2instr*16rows=256; B1 waves0-3 *16rows=64; B2 waves4-7 =64.
// Compute: wave (64m x 32f): wm=(w>>1)*64, wf=(w&1)*32 -> 256x64.
// Swizzle (64B rows, 4 slots): f(row)=(row>>1)&3; write src slot (l&3)^((l>>3)&3),
// read slot (l>>4)^((lm>>1)&3). 2 lanes/bank-quad per quarter-wave = conflict-free.
__global__ __launch_bounds__(512, 4) void gemm1_mfma(
    const __bf16* __restrict__ Xb, const __bf16* __restrict__ W1t,
    const __bf16* __restrict__ W2t, const float* __restrict__ b1,
    const float* __restrict__ b2, const int* __restrict__ pairTok,
    const int* __restrict__ rbe, const __bf16* __restrict__ zpg,
    __bf16* __restrict__ hidden)
{
    int b = blockIdx.x;
    int e = rbe[b];
    if (e < 0) return;
    int fblk = blockIdx.y * 64;

    __shared__ __bf16 smem[2][12288];

    int tid = threadIdx.x, w = tid >> 6, l = tid & 63;
    int r0 = b * MT;
    int ss4 = (l & 3) ^ ((l >> 3) & 3);

    const __bf16* aptr[2];
#pragma unroll
    for (int j = 0; j < 2; ++j) {
        int row = w * 32 + j * 16 + (l >> 2);
        int tok = pairTok[r0 + row];
        aptr[j] = (tok >= 0 ? Xb + (size_t)tok * D_MODEL : zpg) + ss4 * 8;
    }
    const __bf16* wsrc = (w < 4) ? W1t : W2t;
    int wb = w & 3;
    const __bf16* bptr = wsrc + ((size_t)e << 22)
        + (size_t)(fblk + wb * 16 + (l >> 2)) * D_MODEL + ss4 * 8;
    int bdst = (w < 4 ? 8192 : 10240) + wb * 512;

    int wm = (w >> 1) * 64, wf = (w & 1) * 32;
    int lm = l & 15;
    int sl = (((l >> 4) ^ ((lm >> 1) & 3)) << 3);

    f32x4 c1[4][2], c2[4][2];
#pragma unroll
    for (int mi = 0; mi < 4; ++mi)
#pragma unroll
        for (int fj = 0; fj < 2; ++fj) {
            c1[mi][fj] = (f32x4){0.f, 0.f, 0.f, 0.f};
            c2[mi][fj] = (f32x4){0.f, 0.f, 0.f, 0.f};
        }

    auto stage = [&](int buf, int k0) {
        __bf16* base = &smem[buf][0];
        async16(aptr[0] + k0, base + w * 1024 + l * 8);
        async16(aptr[1] + k0, base + w * 1024 + 512 + l * 8);
        async16(bptr + k0, base + bdst + l * 8);
    };

    stage(0, 0);
    __syncthreads();
    const int NT = D_MODEL / 32;   // 32
    for (int t = 0; t < NT; ++t) {
        int cur = t & 1;
        if (t + 1 < NT) stage(cur ^ 1, (t + 1) * 32);
        const __bf16* sb = &smem[cur][0];
        bf16x8 a[4];
#pragma unroll
        for (int mi = 0; mi < 4; ++mi)
            a[mi] = *reinterpret_cast<const bf16x8*>(sb + (wm + mi * 16 + lm) * 32 + sl);
#pragma unroll
        for (int fj = 0; fj < 2; ++fj) {
            int frow = (wf + fj * 16 + lm) * 32 + sl;
            bf16x8 bv1 = *reinterpret_cast<const bf16x8*>(sb + 8192 + frow);
            bf16x8 bv2 = *reinterpret_cast<const bf16x8*>(sb + 10240 + frow);
#pragma unroll
            for (int mi = 0; mi < 4; ++mi) {
                c1[mi][fj] = __builtin_amdgcn_mfma_f32_16x16x32_bf16(a[mi], bv1, c1[mi][fj], 0, 0, 0);
                c2[mi][fj] = __builtin_amdgcn_mfma_f32_16x16x32_bf16(a[mi], bv2, c2[mi][fj], 0, 0, 0);
            }
        }
        __syncthreads();
    }

#pragma unroll
    for (int fj = 0; fj < 2; ++fj) {
        int f = fblk + wf + fj * 16 + lm;
        float b1v = b1[e * D_FF + f];
        float b2v = b2[e * D_FF + f];
#pragma unroll
        for (int mi = 0; mi < 4; ++mi)
#pragma unroll
            for (int r = 0; r < 4; ++r) {
                int m = wm + mi * 16 + (l >> 4) * 4 + r;
                float h1 = c1[mi][fj][r] + b1v;
                float h2 = c2[mi][fj][r] + b2v;
                float g = 0.5f * h1 * (1.f + erff(h1 * 0.70710678118654752f));
                hidden[(size_t)(r0 + m) * D_FF + f] = (__bf16)(g * h2);
            }
    }
}

// ---------------- GEMM2: 128x128, BK=64, K=4096 deep, po-store (no atomics) ----------------
// LDS elems/buf: A[128*64]=8192 @0 | B[128*64]=8192 @8192 = 16384 (32KB), x2 = 64KB.
// Coverage: A 8w*2instr*8rows=128; B same. Compute: wave (32m x 64n):
// wm=(w>>1)*32, wn=(w&1)*64 -> 128x128. 8-slot swizzle (HW-verified 0 conflicts).
__global__ __launch_bounds__(512, 4) void gemm2_mfma(
    const __bf16* __restrict__ hidden, const __bf16* __restrict__ W3t,
    const float* __restrict__ b3, const int* __restrict__ rbe,
    float* __restrict__ po)
{
    int rb = blockIdx.x;           // 128-row block
    int e = rbe[rb >> 1];
    if (e < 0) return;
    int dblk = blockIdx.y * 128;

    __shared__ __bf16 smem[2][16384];

    int tid = threadIdx.x, w = tid >> 6, l = tid & 63;
    int ss8 = (l & 7) ^ (l >> 3);
    int r0m = rb * 128;

    const __bf16* abase = hidden + (size_t)(r0m + w * 16 + (l >> 3)) * D_FF + ss8 * 8;
    const __bf16* bbase = W3t + ((size_t)e << 22)
        + (size_t)(dblk + w * 16 + (l >> 3)) * D_FF + ss8 * 8;

    int wm = (w >> 1) * 32, wn = (w & 1) * 64;
    int lm = l & 15;

    f32x4 c[2][4];
#pragma unroll
    for (int mi = 0; mi < 2; ++mi)
#pragma unroll
        for (int nj = 0; nj < 4; ++nj) c[mi][nj] = (f32x4){0.f, 0.f, 0.f, 0.f};

    auto stage = [&](int buf, int k0) {
        __bf16* base = &smem[buf][0];
        async16(abase + k0,              base + w * 1024 + l * 8);
        async16(abase + 8 * D_FF + k0,   base + w * 1024 + 512 + l * 8);
        async16(bbase + k0,              base + 8192 + w * 1024 + l * 8);
        async16(bbase + 8 * D_FF + k0,   base + 8192 + w * 1024 + 512 + l * 8);
    };

    stage(0, 0);
    __syncthreads();
    const int NT = D_FF / 64;   // 64
    for (int t = 0; t < NT; ++t) {
        int cur = t & 1;
        if (t + 1 < NT) stage(cur ^ 1, (t + 1) * 64);
        const __bf16* sb = &smem[cur][0];
#pragma unroll
        for (int ks = 0; ks < 2; ++ks) {
            int sl = (((ks * 4 + (l >> 4)) ^ (l & 7)) << 3);
            bf16x8 a[2];
#pragma unroll
            for (int mi = 0; mi < 2; ++mi)
                a[mi] = *reinterpret_cast<const bf16x8*>(sb + (wm + mi * 16 + lm) * 64 + sl);
#pragma unroll
            for (int nj = 0; nj < 4; ++nj) {
                bf16x8 bv = *reinterpret_cast<const bf16x8*>(sb + 8192 + (wn + nj * 16 + lm) * 64 + sl);
#pragma unroll
                for (int mi = 0; mi < 2; ++mi)
                    c[mi][nj] = __builtin_amdgcn_mfma_f32_16x16x32_bf16(a[mi], bv, c[mi][nj], 0, 0, 0);
            }
        }
        __syncthreads();
    }

#pragma unroll
    for (int nj = 0; nj < 4; ++nj) {
        int d = dblk + wn + nj * 16 + lm;
        float b3v = b3[e * D_MODEL + d];
#pragma unroll
        for (int mi = 0; mi < 2; ++mi)
#pragma unroll
            for (int r = 0; r < 4; ++r) {
                int m = wm + mi * 16 + (l >> 4) * 4 + r;
                po[(size_t)(r0m + m) * D_MODEL + d] = c[mi][nj][r] + b3v;
            }
    }
}

// ---------------- combine: out[t] = w0*po[r0] + w1*po[r1] ----------------
__global__ __launch_bounds__(256) void combine_kernel(
    const float* __restrict__ po, const float* __restrict__ topw,
    const int* __restrict__ pairRow, float* __restrict__ out)
{
    int t = blockIdx.x, tid = threadIdx.x;
    int d = tid * 4;
    float w0 = topw[t * 2], w1 = topw[t * 2 + 1];
    int r0 = pairRow[t * 2], r1 = pairRow[t * 2 + 1];
    float4 v0 = *reinterpret_cast<const float4*>(po + (size_t)r0 * D_MODEL + d);
    float4 v1 = *reinterpret_cast<const float4*>(po + (size_t)r1 * D_MODEL + d);
    float4 o;
    o.x = w0 * v0.x + w1 * v1.x;
    o.y = w0 * v0.y + w1 * v1.y;
    o.z = w0 * v0.z + w1 * v1.z;
    o.w = w0 * v0.w + w1 * v1.w;
    *reinterpret_cast<float4*>(out + (size_t)t * D_MODEL + d) = o;
}

// ================= legacy fallback (64-row blocks on 256-aligned lists) =================
__global__ __launch_bounds__(256) void gemm1_legacy(
    const __bf16* __restrict__ Xb, const float* __restrict__ W1,
    const float* __restrict__ W2, const float* __restrict__ b1,
    const float* __restrict__ b2, const int* __restrict__ pairTok,
    const int* __restrict__ rbe, __bf16* __restrict__ hidden)
{
    int b = blockIdx.x;
    int e = rbe[b >> 2];
    if (e < 0) return;
    int fblk = blockIdx.y * 128;

    __shared__ __bf16 As[64][40];
    __shared__ __bf16 W1s[128][40];
    __shared__ __bf16 W2s[128][40];

    int tid = threadIdx.x;
    int arow = tid >> 2, akoff = (tid & 3) * 8;
    int r0 = b * 64;
    int tok = pairTok[r0 + arow];
    int wk = tid >> 3, wfb = (tid & 7) * 16;
    const float* w1base = W1 + (size_t)e * D_MODEL * D_FF + (size_t)wk * D_FF + fblk + wfb;
    const float* w2base = W2 + (size_t)e * D_MODEL * D_FF + (size_t)wk * D_FF + fblk + wfb;

    int wave = tid >> 6, lane = tid & 63;
    int wm = (wave >> 1) * 32, wf = (wave & 1) * 64;
    int lm = lane & 15, lk = (lane >> 4) * 8;

    __bf16 z = (__bf16)0.f;
    f32x4 c1[2][4], c2[2][4];
#pragma unroll
    for (int mi = 0; mi < 2; ++mi)
#pragma unroll
        for (int fj = 0; fj < 4; ++fj) {
            c1[mi][fj] = (f32x4){0.f, 0.f, 0.f, 0.f};
            c2[mi][fj] = (f32x4){0.f, 0.f, 0.f, 0.f};
        }

    for (int k0 = 0; k0 < D_MODEL; k0 += 32) {
        __syncthreads();
        bf16x8 av = {z, z, z, z, z, z, z, z};
        if (tok >= 0)
            av = *reinterpret_cast<const bf16x8*>(Xb + (size_t)tok * D_MODEL + k0 + akoff);
        *reinterpret_cast<bf16x8*>(&As[arow][akoff]) = av;
        const float* p1 = w1base + (size_t)k0 * D_FF;
        const float* p2 = w2base + (size_t)k0 * D_FF;
#pragma unroll
        for (int j = 0; j < 4; ++j) {
            float4 v = *reinterpret_cast<const float4*>(p1 + j * 4);
            W1s[wfb + j * 4 + 0][wk] = (__bf16)v.x;
            W1s[wfb + j * 4 + 1][wk] = (__bf16)v.y;
            W1s[wfb + j * 4 + 2][wk] = (__bf16)v.z;
            W1s[wfb + j * 4 + 3][wk] = (__bf16)v.w;
            float4 u = *reinterpret_cast<const float4*>(p2 + j * 4);
            W2s[wfb + j * 4 + 0][wk] = (__bf16)u.x;
            W2s[wfb + j * 4 + 1][wk] = (__bf16)u.y;
            W2s[wfb + j * 4 + 2][wk] = (__bf16)u.z;
            W2s[wfb + j * 4 + 3][wk] = (__bf16)u.w;
        }
        __syncthreads();

        bf16x8 a0 = *reinterpret_cast<bf16x8*>(&As[wm + lm][lk]);
        bf16x8 a1 = *reinterpret_cast<bf16x8*>(&As[wm + 16 + lm][lk]);
#pragma unroll
        for (int fj = 0; fj < 4; ++fj) {
            bf16x8 bw1 = *reinterpret_cast<bf16x8*>(&W1s[wf + fj * 16 + lm][lk]);
            c1[0][fj] = __builtin_amdgcn_mfma_f32_16x16x32_bf16(a0, bw1, c1[0][fj], 0, 0, 0);
            c1[1][fj] = __builtin_amdgcn_mfma_f32_16x16x32_bf16(a1, bw1, c1[1][fj], 0, 0, 0);
            bf16x8 bw2 = *reinterpret_cast<bf16x8*>(&W2s[wf + fj * 16 + lm][lk]);
            c2[0][fj] = __builtin_amdgcn_mfma_f32_16x16x32_bf16(a0, bw2, c2[0][fj], 0, 0, 0);
            c2[1][fj] = __builtin_amdgcn_mfma_f32_16x16x32_bf16(a1, bw2, c2[1][fj], 0, 0, 0);
        }
    }

#pragma unroll
    for (int fj = 0; fj < 4; ++fj) {
        int f = fblk + wf + fj * 16 + lm;
        float b1v = b1[e * D_FF + f];
        float b2v = b2[e * D_FF + f];
#pragma unroll
        for (int mi = 0; mi < 2; ++mi)
#pragma unroll
            for (int r = 0; r < 4; ++r) {
                int m = wm + mi * 16 + (lane >> 4) * 4 + r;
                float h1 = c1[mi][fj][r] + b1v;
                float h2 = c2[mi][fj][r] + b2v;
                float g = 0.5f * h1 * (1.f + erff(h1 * 0.70710678118654752f));
                hidden[(size_t)(r0 + m) * D_FF + f] = (__bf16)(g * h2);
            }
    }
}

__global__ __launch_bounds__(256) void gemm2_legacy(
    const __bf16* __restrict__ hidden, const float* __restrict__ W3,
    const float* __restrict__ b3, const int* __restrict__ pairTok,
    const float* __restrict__ pairW, const int* __restrict__ rbe,
    float* __restrict__ out)
{
    int b = blockIdx.x;
    int e = rbe[b >> 2];
    if (e < 0) return;
    int dblk = blockIdx.y * 128;

    __shared__ __bf16 As[64][40];
    __shared__ __bf16 W3s[128][40];

    int tid = threadIdx.x;
    int arow = tid >> 2, akoff = (tid & 3) * 8;
    int r0 = b * 64;
    const __bf16* ap = hidden + (size_t)(r0 + arow) * D_FF + akoff;
    int wk = tid >> 3, wdb = (tid & 7) * 16;
    const float* w3base = W3 + (size_t)e * D_FF * D_MODEL + (size_t)wk * D_MODEL + dblk + wdb;

    int wave = tid >> 6, lane = tid & 63;
    int wm = (wave >> 1) * 32, wf = (wave & 1) * 64;
    int lm = lane & 15, lk = (lane >> 4) * 8;

    f32x4 c[2][4];
#pragma unroll
    for (int mi = 0; mi < 2; ++mi)
#pragma unroll
        for (int dj = 0; dj < 4; ++dj) c[mi][dj] = (f32x4){0.f, 0.f, 0.f, 0.f};

    for (int k0 = 0; k0 < D_FF; k0 += 32) {
        __syncthreads();
        *reinterpret_cast<bf16x8*>(&As[arow][akoff]) =
            *reinterpret_cast<const bf16x8*>(ap + k0);
        const float* p3 = w3base + (size_t)k0 * D_MODEL;
#pragma unroll
        for (int j = 0; j < 4; ++j) {
            float4 v = *reinterpret_cast<const float4*>(p3 + j * 4);
            W3s[wdb + j * 4 + 0][wk] = (__bf16)v.x;
            W3s[wdb + j * 4 + 1][wk] = (__bf16)v.y;
            W3s[wdb + j * 4 + 2][wk] = (__bf16)v.z;
            W3s[wdb + j * 4 + 3][wk] = (__bf16)v.w;
        }
        __syncthreads();

        bf16x8 a0 = *reinterpret_cast<bf16x8*>(&As[wm + lm][lk]);
        bf16x8 a1 = *reinterpret_cast<bf16x8*>(&As[wm + 16 + lm][lk]);
#pragma unroll
        for (int dj = 0; dj < 4; ++dj) {
            bf16x8 bw = *reinterpret_cast<bf16x8*>(&W3s[wf + dj * 16 + lm][lk]);
            c[0][dj] = __builtin_amdgcn_mfma_f32_16x16x32_bf16(a0, bw, c[0][dj], 0, 0, 0);
            c[1][dj] = __builtin_amdgcn_mfma_f32_16x16x32_bf16(a1, bw, c[1][dj], 0, 0, 0);
        }
    }

#pragma unroll
    for (int dj = 0; dj < 4; ++dj) {
        int d = dblk + wf + dj * 16 + lm;
        float b3v = b3[e * D_MODEL + d];
#pragma unroll
        for (int mi = 0; mi < 2; ++mi)
#pragma unroll
            for (int r = 0; r < 4; ++r) {
                int m = wm + mi * 16 + (lane >> 4) * 4 + r;
                int gr = r0 + m;
                int tok = pairTok[gr];
                if (tok >= 0) {
                    float val = c[mi][dj][r] + b3v;
                    atomicAdd(out + (size_t)tok * D_MODEL + d, pairW[gr] * val);
                }
            }
    }
}

extern "C" void kernel_launch(void* const* d_in, const int* in_sizes, int n_in,
                              void* d_out, int out_size, void* d_ws, size_t ws_size,
                              hipStream_t stream)
{
    const float* x  = (const float*)d_in[0];
    const float* Wg = (const float*)d_in[1];
    const float* bg = (const float*)d_in[2];
    const float* W1 = (const float*)d_in[3];
    const float* b1 = (const float*)d_in[4];
    const float* W2 = (const float*)d_in[5];
    const float* b2 = (const float*)d_in[6];
    const float* W3 = (const float*)d_in[7];
    const float* b3 = (const float*)d_in[8];
    float* out = (float*)d_out;

    int N = in_sizes[0] / D_MODEL;
    int npairs = N * 2;
    int maxblk = npairs / MT + NE;     // 24
    int maxrows = maxblk * MT;         // 6144

    char* ws = (char*)d_ws;
    size_t off = 0;
    auto alloc = [&](size_t bytes) -> void* {
        void* p = ws + off;
        off = (off + bytes + 255) & ~(size_t)255;
        return p;
    };
    int*    topidx  = (int*)   alloc((size_t)npairs * 4);
    float*  topw    = (float*) alloc((size_t)npairs * 4);
    int*    pairTok = (int*)   alloc((size_t)maxrows * 4);
    float*  pairW   = (float*) alloc((size_t)maxrows * 4);
    int*    rbe     = (int*)   alloc((size_t)maxblk * 4);
    int*    pairRow = (int*)   alloc((size_t)npairs * 4);
    __bf16* Xb      = (__bf16*)alloc((size_t)N * D_MODEL * 2);
    __bf16* hidden  = (__bf16*)alloc((size_t)maxrows * D_FF * 2);
    __bf16* zpg     = (__bf16*)alloc(4096);
    const size_t WSZ = (size_t)NE * D_MODEL * D_FF * 2;   // 64 MB per matrix
    __bf16* W1t = (__bf16*)alloc(WSZ);
    __bf16* W2t = (__bf16*)alloc(WSZ);
    __bf16* W3t = (__bf16*)alloc(WSZ);
    float*  po  = (float*)W1t;   // overlay: W1t dead after gemm1 (25MB < 64MB)
    bool primary = (off <= ws_size);
    (void)n_in;

    hipMemsetAsync(d_out, 0, (size_t)out_size * sizeof(float), stream);
    router_kernel<<<N, 256, 0, stream>>>(x, Wg, bg, topidx, topw, Xb);
    build_lists_kernel<<<1, 256, 0, stream>>>(topidx, topw, pairTok, pairW, rbe,
                                              pairRow, npairs, maxrows, maxblk);
    if (primary) {
        hipMemsetAsync(zpg, 0, 4096, stream);
        transpose_cvt_kernel<<<dim3(D_FF / 64, D_MODEL / 64, NE), 256, 0, stream>>>(
            W1, W1t, D_MODEL, D_FF);
        transpose_cvt_kernel<<<dim3(D_FF / 64, D_MODEL / 64, NE), 256, 0, stream>>>(
            W2, W2t, D_MODEL, D_FF);
        transpose_cvt_kernel<<<dim3(D_MODEL / 64, D_FF / 64, NE), 256, 0, stream>>>(
            W3, W3t, D_FF, D_MODEL);
        gemm1_mfma<<<dim3(maxblk, D_FF / 64), 512, 0, stream>>>(
            Xb, W1t, W2t, b1, b2, pairTok, rbe, zpg, hidden);
        gemm2_mfma<<<dim3(maxblk * 2, D_MODEL / 128), 512, 0, stream>>>(
            hidden, W3t, b3, rbe, po);
        combine_kernel<<<N, 256, 0, stream>>>(po, topw, pairRow, out);
    } else {
        gemm1_legacy<<<dim3(maxblk * 4, D_FF / 128), 256, 0, stream>>>(
            Xb, W1, W2, b1, b2, pairTok, rbe, hidden);
        gemm2_legacy<<<dim3(maxblk * 4, D_MODEL / 128), 256, 0, stream>>>(
            hidden, W3, b3, pairTok, pairW, rbe, out);
    }
}